// Round 3
// baseline (188.632 us; speedup 1.0000x reference)
//
#include <hip/hip_runtime.h>
#include <math.h>

// Problem constants
#define MM 4
#define BB 256
#define KK 64
#define HH 1024
#define NN 50
#define EE 1225
#define PP 64
#define CTOT 1375   // E + N*3
#define NPAD 1408   // cols padded to 22*64

// R3 MEASUREMENT ROUND: k2 is launched K2_REPS times (idempotent after the
// SnegP change below). Delta vs R2 dur_us decomposes the pipeline:
//   t_k2 ~= (dur_R3 - dur_R2)/4 - gap.   REVERT K2_REPS to 1 in R4.
#define K2_REPS 5

typedef short short8 __attribute__((ext_vector_type(8)));
typedef float floatx4 __attribute__((ext_vector_type(4)));
typedef unsigned short ushort;

__device__ __forceinline__ ushort f2bf(float f) {
    union { float f; unsigned u; } v; v.f = f;
    unsigned r = v.u + 0x7fffu + ((v.u >> 16) & 1u);
    return (ushort)(r >> 16);
}

__device__ __forceinline__ float logsigm(float l) {
    // log sigmoid(-l) = -(max(l,0) + log1p(exp(-|l|)))
    return -(fmaxf(l, 0.0f) + log1pf(expf(-fabsf(l))));
}

__device__ __forceinline__ float wsum64(float v) {
    #pragma unroll
    for (int m = 1; m < 64; m <<= 1) v += __shfl_xor(v, m);
    return v;
}
__device__ __forceinline__ float wmax64(float v) {
    #pragma unroll
    for (int m = 1; m < 64; m <<= 1) v = fmaxf(v, __shfl_xor(v, m));
    return v;
}

// kA: fused weight transpose (blocks 256..607) + per-graph work (blocks 0..255)
// + perm-inverse table build (blocks 608..611, graph-independent, feeds k4).
// NOTE (R4/R6 post-mortems): keep this a plain 3-kernel chain. Cooperative
// grid-sync fusion cost +78 us; atomic producer-consumer fusion cost +46 us.
__global__ __launch_bounds__(256) void kA(const float* __restrict__ mean,
                                          const float* __restrict__ logvar,
                                          const float* __restrict__ eps,
                                          const float* __restrict__ W1,
                                          const float* __restrict__ b1,
                                          const float* __restrict__ WA,
                                          const float* __restrict__ WF,
                                          const float* __restrict__ A,
                                          const int*   __restrict__ perms,
                                          ushort* __restrict__ hB,
                                          ushort* __restrict__ Wt,
                                          int*   __restrict__ edgesG,
                                          int*   __restrict__ cntG,
                                          float* __restrict__ kldG,
                                          int*   __restrict__ ipG) {
    const int t = threadIdx.x;
    __shared__ float smem[64 * 65];
    __shared__ int cnt;

    if (blockIdx.x < 256) {
        // ---- per-graph block ----
        const int b = blockIdx.x;
        float4* z4 = (float4*)smem;
        if (t == 0) cnt = 0;
        if (t < 64) {
            float mv = mean[b * 64 + t];
            float lv = logvar[b * 64 + t];
            float sd = expf(0.5f * lv);
            float4 z;
            z.x = mv + sd * eps[(0 * BB + b) * 64 + t];
            z.y = mv + sd * eps[(1 * BB + b) * 64 + t];
            z.z = mv + sd * eps[(2 * BB + b) * 64 + t];
            z.w = mv + sd * eps[(3 * BB + b) * 64 + t];
            z4[t] = z;
            // KLD (wave 0, one lane per latent dim)
            float term = 0.5f * (expf(lv) + mv * mv - 1.0f - lv);
            term = wsum64(term);
            if (t == 0) kldG[b] = term;
        }
        __syncthreads();
        const int j0 = t * 4;
        float acc[4][4] = {};   // [m][jc]
        #pragma unroll 8
        for (int k = 0; k < 64; k++) {
            float4 w = *(const float4*)&W1[k * HH + j0];
            float4 z = z4[k];
            acc[0][0] += z.x * w.x; acc[0][1] += z.x * w.y; acc[0][2] += z.x * w.z; acc[0][3] += z.x * w.w;
            acc[1][0] += z.y * w.x; acc[1][1] += z.y * w.y; acc[1][2] += z.y * w.z; acc[1][3] += z.y * w.w;
            acc[2][0] += z.z * w.x; acc[2][1] += z.z * w.y; acc[2][2] += z.z * w.z; acc[2][3] += z.z * w.w;
            acc[3][0] += z.w * w.x; acc[3][1] += z.w * w.y; acc[3][2] += z.w * w.z; acc[3][3] += z.w * w.w;
        }
        float4 bb = *(const float4*)&b1[j0];
        #pragma unroll
        for (int m = 0; m < 4; m++) {
            unsigned u0 = ((unsigned)f2bf(fmaxf(acc[m][0] + bb.x, 0.f))) |
                          ((unsigned)f2bf(fmaxf(acc[m][1] + bb.y, 0.f)) << 16);
            unsigned u1 = ((unsigned)f2bf(fmaxf(acc[m][2] + bb.z, 0.f))) |
                          ((unsigned)f2bf(fmaxf(acc[m][3] + bb.w, 0.f)) << 16);
            uint2 u; u.x = u0; u.y = u1;
            *(uint2*)&hB[(b * 4 + m) * HH + j0] = u;
        }
        // ---- edge extraction: coalesced scan of A[b], lower triangle ----
        for (int x = t; x < 2500; x += 256) {
            int i = x / NN, j = x - i * NN;
            if (j < i) {
                float a = A[b * 2500 + x];
                if (a != 0.0f) { int id = atomicAdd(&cnt, 1); edgesG[b * 256 + id] = (i << 8) | j; }
            }
        }
        __syncthreads();
        if (t == 0) cntG[b] = cnt;
    } else if (blockIdx.x < 608) {
        // ---- Wt[n][k] = transpose of [WA | WF] (bf16, zero-padded cols) ----
        const int id = blockIdx.x - 256;
        const int kt = id & 15, nt = id >> 4;
        float* T = smem;   // [64][65]
        const int k0 = kt * 64, n0 = nt * 64;
        #pragma unroll
        for (int i = 0; i < 16; i++) {
            int x = i * 256 + t;
            int kk = x >> 6, nn = x & 63;
            int gn = n0 + nn, gk = k0 + kk;
            float v = 0.f;
            if (gn < EE)        v = WA[gk * EE + gn];
            else if (gn < CTOT) v = WF[gk * 150 + (gn - EE)];
            T[kk * 65 + nn] = v;
        }
        __syncthreads();
        #pragma unroll
        for (int i = 0; i < 16; i++) {
            int x = i * 256 + t;
            int nn = x >> 6, kk = x & 63;
            Wt[(n0 + nn) * 1024 + k0 + kk] = f2bf(T[kk * 65 + nn]);
        }
    } else {
        // ---- ipG[p][node] = position of node in perm p (stride 51, b-independent) ----
        const int id = blockIdx.x - 608;   // 0..3, 16 perms each
        for (int x = id * 800 + t; x < (id + 1) * 800; x += 256) {
            int p = x / NN, i = x - p * NN;
            ipG[p * 51 + perms[x]] = i;
        }
    }
}

// K2: MFMA GEMM logits[1024][1375] = hB @ Wt^T with fused epilogue.
// Double-buffered LDS ping-pong, one barrier per K-chunk.
// R3: Sneg atomics -> plain stores of per-(ct,wn) partials SnegP[b][m][44]
// (makes k2 idempotent so the measurement multi-launch is bit-safe, and
// removes global atomic contention). k4 reduces the 44 partials.
// 64x64 tile, grid 22x16 = 352 blocks, 4 waves (2x2), wave 32x32. LDS 36.9KB.
__global__ __launch_bounds__(256) void k2(const ushort* __restrict__ hB,
                                          const ushort* __restrict__ Wt,
                                          const float* __restrict__ bA,
                                          const float* __restrict__ bF,
                                          float* __restrict__ Lbar,
                                          float* __restrict__ SnegP,
                                          float* __restrict__ lgF) {
    const int ct = blockIdx.x;   // 0..21
    const int rt = blockIdx.y;   // 0..15
    const int t = threadIdx.x;
    const int w = t >> 6, lane = t & 63;
    const int wm = w >> 1, wn = w & 1;
    const int quad = lane >> 4, l16 = lane & 15;
    __shared__ short As[2][64][72];
    __shared__ short Bs[2][64][72];
    floatx4 acc[2][2] = {};
    const int row0 = rt * 64, col0 = ct * 64;

    const int r0 = t >> 3, koA = (t & 7) * 8;
    const int r1 = r0 + 32;
    const ushort* pA0 = hB + (row0 + r0) * 1024 + koA;
    const ushort* pA1 = hB + (row0 + r1) * 1024 + koA;
    const ushort* pB0 = Wt + (col0 + r0) * 1024 + koA;
    const ushort* pB1 = Wt + (col0 + r1) * 1024 + koA;

    short8 ra0 = *(const short8*)(pA0);
    short8 ra1 = *(const short8*)(pA1);
    short8 rb0 = *(const short8*)(pB0);
    short8 rb1 = *(const short8*)(pB1);
    *(short8*)&As[0][r0][koA] = ra0;
    *(short8*)&As[0][r1][koA] = ra1;
    *(short8*)&Bs[0][r0][koA] = rb0;
    *(short8*)&Bs[0][r1][koA] = rb1;
    __syncthreads();

    int cur = 0;
    for (int ch = 0; ch < 16; ch++) {
        if (ch < 15) {
            const int off = (ch + 1) * 64;
            ra0 = *(const short8*)(pA0 + off);
            ra1 = *(const short8*)(pA1 + off);
            rb0 = *(const short8*)(pB0 + off);
            rb1 = *(const short8*)(pB1 + off);
        }
        #pragma unroll
        for (int kk = 0; kk < 2; kk++) {
            int ko = kk * 32 + quad * 8;
            short8 a0 = *(const short8*)&As[cur][wm * 32 + l16][ko];
            short8 a1 = *(const short8*)&As[cur][wm * 32 + 16 + l16][ko];
            short8 b0 = *(const short8*)&Bs[cur][wn * 32 + l16][ko];
            short8 b1 = *(const short8*)&Bs[cur][wn * 32 + 16 + l16][ko];
            acc[0][0] = __builtin_amdgcn_mfma_f32_16x16x32_bf16(a0, b0, acc[0][0], 0, 0, 0);
            acc[0][1] = __builtin_amdgcn_mfma_f32_16x16x32_bf16(a0, b1, acc[0][1], 0, 0, 0);
            acc[1][0] = __builtin_amdgcn_mfma_f32_16x16x32_bf16(a1, b0, acc[1][0], 0, 0, 0);
            acc[1][1] = __builtin_amdgcn_mfma_f32_16x16x32_bf16(a1, b1, acc[1][1], 0, 0, 0);
        }
        if (ch < 15) {
            *(short8*)&As[cur ^ 1][r0][koA] = ra0;
            *(short8*)&As[cur ^ 1][r1][koA] = ra1;
            *(short8*)&Bs[cur ^ 1][r0][koA] = rb0;
            *(short8*)&Bs[cur ^ 1][r1][koA] = rb1;
            __syncthreads();
            cur ^= 1;
        }
    }

    // Epilogue: C/D layout col=lane&15, row=quad*4+reg -> lane's 4 regs = graph b, m=0..3
    #pragma unroll
    for (int mi = 0; mi < 2; mi++) {
        const int grow = row0 + wm * 32 + mi * 16 + quad * 4;
        const int b = grow >> 2;
        float sn0 = 0.f, sn1 = 0.f, sn2 = 0.f, sn3 = 0.f;
        #pragma unroll
        for (int ni = 0; ni < 2; ni++) {
            int gc = col0 + wn * 32 + ni * 16 + l16;
            floatx4 a = acc[mi][ni];
            if (gc < EE) {
                float bias = bA[gc];
                float l0 = a[0] + bias, l1 = a[1] + bias, l2 = a[2] + bias, l3 = a[3] + bias;
                Lbar[b * EE + gc] = 0.25f * (l0 + l1 + l2 + l3);
                sn0 += logsigm(l0); sn1 += logsigm(l1); sn2 += logsigm(l2); sn3 += logsigm(l3);
            } else if (gc < CTOT) {
                int c2 = gc - EE;
                float bias = bF[c2];
                lgF[(b * 4 + 0) * 150 + c2] = a[0] + bias;
                lgF[(b * 4 + 1) * 150 + c2] = a[1] + bias;
                lgF[(b * 4 + 2) * 150 + c2] = a[2] + bias;
                lgF[(b * 4 + 3) * 150 + c2] = a[3] + bias;
            }
        }
        #pragma unroll
        for (int msk = 1; msk < 16; msk <<= 1) {
            sn0 += __shfl_xor(sn0, msk);
            sn1 += __shfl_xor(sn1, msk);
            sn2 += __shfl_xor(sn2, msk);
            sn3 += __shfl_xor(sn3, msk);
        }
        if (l16 == 0) {
            const int o = ct * 2 + wn;
            SnegP[(b * 4 + 0) * 44 + o] = sn0;
            SnegP[(b * 4 + 1) * 44 + o] = sn1;
            SnegP[(b * 4 + 2) * 44 + o] = sn2;
            SnegP[(b * 4 + 3) * 44 + o] = sn3;
        }
    }
}

// K4: per-graph finalization. grid 256, 512 threads (8 waves).
// lane = permutation (64 lanes = 64 perms), wave = edge-stripe (8-way).
// R3: also reduces the 44 SnegP partials per (b,m) (replaces Sneg atomics).
__global__ __launch_bounds__(512) void k4(const float* __restrict__ Fx,
                                          const float* __restrict__ coeff,
                                          const int* __restrict__ ipG,
                                          const float* __restrict__ Lbar,
                                          const float* __restrict__ SnegP,
                                          const float* __restrict__ lgF,
                                          const int* __restrict__ edgesG,
                                          const int* __restrict__ cntG,
                                          const float* __restrict__ kldG,
                                          float* __restrict__ out) {
    const int b = blockIdx.x;
    const int t = threadIdx.x;
    const int w = t >> 6, lane = t & 63;
    __shared__ int   ip[PP * 51];      // [perm][node], stride 51 (odd -> 2-way banks)
    __shared__ float LbF[NN * 51];     // full symmetric matrix
    __shared__ int   edges[256];
    __shared__ float lgfs[600];
    __shared__ float mred[4], snegR[4];
    __shared__ float psum[8][64];

    const int ne = cntG[b];
    for (int x = t; x < PP * 51; x += 512) ip[x] = ipG[x];
    for (int x = t; x < 2500; x += 512) {
        int i = x / NN, j = x - i * NN;
        if (j < i) {
            float v = Lbar[b * EE + i * (i - 1) / 2 + j];
            LbF[i * 51 + j] = v;
            LbF[j * 51 + i] = v;
        }
    }
    for (int x = t; x < 600; x += 512) lgfs[x] = lgF[b * 600 + x];
    if (t < ne) edges[t] = edgesG[b * 256 + t];
    __syncthreads();

    // perm partial sums: all 64 perms in flight per wave, edges striped by wave
    {
        const int ipB = lane * 51;
        float acc = 0.f;
        for (int x = w; x < ne; x += 8) {
            int ed = edges[x];
            int iu = ip[ipB + (ed >> 8)];
            int iv = ip[ipB + (ed & 255)];
            acc += LbF[iu * 51 + iv];
        }
        psum[w][lane] = acc;
    }

    // Fx terms + Sneg partial reduce: waves 0..3 handle sample m = w
    if (w < 4) {
        float l0 = 0.f, l1 = 0.f, l2 = -INFINITY, x0 = 0.f, x1 = 0.f, x2 = 0.f;
        bool v = lane < NN;
        if (v) {
            l0 = lgfs[w * 150 + lane * 3 + 0];
            l1 = lgfs[w * 150 + lane * 3 + 1];
            l2 = lgfs[w * 150 + lane * 3 + 2];
            x0 = Fx[b * 150 + lane * 3 + 0];
            x1 = Fx[b * 150 + lane * 3 + 1];
            x2 = Fx[b * 150 + lane * 3 + 2];
        }
        float mx = wmax64(l2);
        float es = v ? expf(l2 - mx) : 0.f;
        es = wsum64(es);
        float lse = mx + logf(es);
        float val = 0.f;
        if (v) {
            val = coeff[0] * (logsigm(l0) + x0 * l0)
                + coeff[1] * (logsigm(l1) + x1 * l1)
                + coeff[2] * (x2 * (l2 - lse));
        }
        val = wsum64(val);
        float sv = (lane < 44) ? SnegP[(b * 4 + w) * 44 + lane] : 0.f;
        sv = wsum64(sv);
        if (lane == 0) { mred[w] = val; snegR[w] = sv; }
    }
    __syncthreads();

    if (w == 0) {
        float s = psum[0][lane];
        #pragma unroll
        for (int i = 1; i < 8; i++) s += psum[i][lane];
        float dmax = wmax64(s);
        if (lane == 0) {
            float sbar = 0.25f * (snegR[0] + snegR[1] + snegR[2] + snegR[3]);
            float fxv  = 0.25f * (mred[0] + mred[1] + mred[2] + mred[3]);
            out[b] = (sbar + dmax) + fxv - kldG[b];
        }
    }
}

extern "C" void kernel_launch(void* const* d_in, const int* in_sizes, int n_in,
                              void* d_out, int out_size, void* d_ws, size_t ws_size,
                              hipStream_t stream) {
    const float* mean   = (const float*)d_in[0];
    const float* logvar = (const float*)d_in[1];
    const float* eps    = (const float*)d_in[2];
    const float* W1     = (const float*)d_in[3];
    const float* b1     = (const float*)d_in[4];
    const float* WA     = (const float*)d_in[5];
    const float* bA     = (const float*)d_in[6];
    const float* WF     = (const float*)d_in[7];
    const float* bF     = (const float*)d_in[8];
    const float* A      = (const float*)d_in[9];
    const float* Fx     = (const float*)d_in[10];
    const float* coeff  = (const float*)d_in[11];
    const int*   perms  = (const int*)d_in[12];
    float* out = (float*)d_out;

    ushort* Wt   = (ushort*)d_ws;               // 1408*1024 bf16
    ushort* hB   = Wt + NPAD * 1024;            // 1024*1024 bf16
    float*  Lbar = (float*)(hB + 1024 * 1024);  // 256*1225
    float*  SnegP = Lbar + BB * EE;             // 256*4*44 partials (written by k2)
    float*  lgF  = SnegP + 256 * 4 * 44;        // 1024*150
    int*    edgesG = (int*)(lgF + 1024 * 150);  // 256*256
    int*    cntG   = edgesG + 256 * 256;        // 256
    float*  kldG   = (float*)(cntG + 256);      // 256
    int*    ipG    = (int*)(kldG + 256);        // 64*51

    kA<<<dim3(612), dim3(256), 0, stream>>>(mean, logvar, eps, W1, b1, WA, WF, A, perms,
                                            hB, Wt, edgesG, cntG, kldG, ipG);
    for (int r = 0; r < K2_REPS; r++)
        k2<<<dim3(22, 16), dim3(256), 0, stream>>>(hB, Wt, bA, bF, Lbar, SnegP, lgF);
    k4<<<dim3(BB), dim3(512), 0, stream>>>(Fx, coeff, ipG, Lbar, SnegP, lgF,
                                           edgesG, cntG, kldG, out);
}

// Round 5
// 141.464 us; speedup vs baseline: 1.3334x; 1.3334x over previous
//
#include <hip/hip_runtime.h>
#include <math.h>

// Problem constants
#define MM 4
#define BB 256
#define KK 64
#define HH 1024
#define NN 50
#define EE 1225
#define PP 64
#define CTOT 1375   // E + N*3
#define NPAD 1408   // cols padded to 22*64

// R3 measurement: t_k2 + gap = (188.6 - 125.4)/4 = 15.8 us -> k2 ~ 11-13 us.
// R4: k2 rebuilt as barrier-free direct-from-L2 GEMM (see k2 comment).
// R5: identical resubmission — R4 bench was an infra failure (container died),
// not a kernel signal.

typedef short short8 __attribute__((ext_vector_type(8)));
typedef float floatx4 __attribute__((ext_vector_type(4)));
typedef unsigned short ushort;

__device__ __forceinline__ ushort f2bf(float f) {
    union { float f; unsigned u; } v; v.f = f;
    unsigned r = v.u + 0x7fffu + ((v.u >> 16) & 1u);
    return (ushort)(r >> 16);
}

__device__ __forceinline__ float logsigm(float l) {
    // log sigmoid(-l) = -(max(l,0) + log1p(exp(-|l|)))
    return -(fmaxf(l, 0.0f) + log1pf(expf(-fabsf(l))));
}

__device__ __forceinline__ float wsum64(float v) {
    #pragma unroll
    for (int m = 1; m < 64; m <<= 1) v += __shfl_xor(v, m);
    return v;
}
__device__ __forceinline__ float wmax64(float v) {
    #pragma unroll
    for (int m = 1; m < 64; m <<= 1) v = fmaxf(v, __shfl_xor(v, m));
    return v;
}

// kA: fused weight transpose (blocks 256..607) + per-graph work (blocks 0..255)
// + perm-inverse table build (blocks 608..611, graph-independent, feeds k4).
// NOTE (R4/R6 post-mortems of prior session): keep a plain 3-kernel chain.
// Cooperative grid-sync fusion cost +78 us; atomic producer-consumer +46 us.
__global__ __launch_bounds__(256) void kA(const float* __restrict__ mean,
                                          const float* __restrict__ logvar,
                                          const float* __restrict__ eps,
                                          const float* __restrict__ W1,
                                          const float* __restrict__ b1,
                                          const float* __restrict__ WA,
                                          const float* __restrict__ WF,
                                          const float* __restrict__ A,
                                          const int*   __restrict__ perms,
                                          ushort* __restrict__ hB,
                                          ushort* __restrict__ Wt,
                                          int*   __restrict__ edgesG,
                                          int*   __restrict__ cntG,
                                          float* __restrict__ kldG,
                                          int*   __restrict__ ipG) {
    const int t = threadIdx.x;
    __shared__ float smem[64 * 65];
    __shared__ int cnt;

    if (blockIdx.x < 256) {
        // ---- per-graph block ----
        const int b = blockIdx.x;
        float4* z4 = (float4*)smem;
        if (t == 0) cnt = 0;
        if (t < 64) {
            float mv = mean[b * 64 + t];
            float lv = logvar[b * 64 + t];
            float sd = expf(0.5f * lv);
            float4 z;
            z.x = mv + sd * eps[(0 * BB + b) * 64 + t];
            z.y = mv + sd * eps[(1 * BB + b) * 64 + t];
            z.z = mv + sd * eps[(2 * BB + b) * 64 + t];
            z.w = mv + sd * eps[(3 * BB + b) * 64 + t];
            z4[t] = z;
            // KLD (wave 0, one lane per latent dim)
            float term = 0.5f * (expf(lv) + mv * mv - 1.0f - lv);
            term = wsum64(term);
            if (t == 0) kldG[b] = term;
        }
        __syncthreads();
        const int j0 = t * 4;
        float acc[4][4] = {};   // [m][jc]
        #pragma unroll 8
        for (int k = 0; k < 64; k++) {
            float4 w = *(const float4*)&W1[k * HH + j0];
            float4 z = z4[k];
            acc[0][0] += z.x * w.x; acc[0][1] += z.x * w.y; acc[0][2] += z.x * w.z; acc[0][3] += z.x * w.w;
            acc[1][0] += z.y * w.x; acc[1][1] += z.y * w.y; acc[1][2] += z.y * w.z; acc[1][3] += z.y * w.w;
            acc[2][0] += z.z * w.x; acc[2][1] += z.z * w.y; acc[2][2] += z.z * w.z; acc[2][3] += z.z * w.w;
            acc[3][0] += z.w * w.x; acc[3][1] += z.w * w.y; acc[3][2] += z.w * w.z; acc[3][3] += z.w * w.w;
        }
        float4 bb = *(const float4*)&b1[j0];
        #pragma unroll
        for (int m = 0; m < 4; m++) {
            unsigned u0 = ((unsigned)f2bf(fmaxf(acc[m][0] + bb.x, 0.f))) |
                          ((unsigned)f2bf(fmaxf(acc[m][1] + bb.y, 0.f)) << 16);
            unsigned u1 = ((unsigned)f2bf(fmaxf(acc[m][2] + bb.z, 0.f))) |
                          ((unsigned)f2bf(fmaxf(acc[m][3] + bb.w, 0.f)) << 16);
            uint2 u; u.x = u0; u.y = u1;
            *(uint2*)&hB[(b * 4 + m) * HH + j0] = u;
        }
        // ---- edge extraction: coalesced scan of A[b], lower triangle ----
        for (int x = t; x < 2500; x += 256) {
            int i = x / NN, j = x - i * NN;
            if (j < i) {
                float a = A[b * 2500 + x];
                if (a != 0.0f) { int id = atomicAdd(&cnt, 1); edgesG[b * 256 + id] = (i << 8) | j; }
            }
        }
        __syncthreads();
        if (t == 0) cntG[b] = cnt;
    } else if (blockIdx.x < 608) {
        // ---- Wt[n][k] = transpose of [WA | WF] (bf16, zero-padded cols) ----
        const int id = blockIdx.x - 256;
        const int kt = id & 15, nt = id >> 4;
        float* T = smem;   // [64][65]
        const int k0 = kt * 64, n0 = nt * 64;
        #pragma unroll
        for (int i = 0; i < 16; i++) {
            int x = i * 256 + t;
            int kk = x >> 6, nn = x & 63;
            int gn = n0 + nn, gk = k0 + kk;
            float v = 0.f;
            if (gn < EE)        v = WA[gk * EE + gn];
            else if (gn < CTOT) v = WF[gk * 150 + (gn - EE)];
            T[kk * 65 + nn] = v;
        }
        __syncthreads();
        #pragma unroll
        for (int i = 0; i < 16; i++) {
            int x = i * 256 + t;
            int nn = x >> 6, kk = x & 63;
            Wt[(n0 + nn) * 1024 + k0 + kk] = f2bf(T[kk * 65 + nn]);
        }
    } else {
        // ---- ipG[p][node] = position of node in perm p (stride 51, b-independent) ----
        const int id = blockIdx.x - 608;   // 0..3, 16 perms each
        for (int x = id * 800 + t; x < (id + 1) * 800; x += 256) {
            int p = x / NN, i = x - p * NN;
            ipG[p * 51 + perms[x]] = i;
        }
    }
}

// K2 (R4): BARRIER-FREE direct-from-L2 MFMA GEMM.
// Diagnosis: old LDS/barrier version was latency-bound (~12 us measured via
// 5x-launch decomposition): 16 chunks x {barrier, ds round-trip, L2 prefetch}
// with only ~1.4 blocks/CU resident -> zero TLP, every latency exposed.
// Fix: MFMA fragments (lane l16 = row, quad = k-subgroup, 16B/lane) load
// DIRECTLY from global (hB/Wt are L2-resident, ~5 MB). No __syncthreads, no
// LDS. Explicit 2-chunk double buffer with NAMED buffers (static indexing
// only -> no scratch) keeps 8-16 global_load_dwordx4 in flight per wave; ILP
// supplies the latency hiding the small grid can't. ~100 VGPR.
// 64x64 tile, grid 22x16 = 352 blocks, 4 waves (2x2), wave 32x32.
__global__ __launch_bounds__(256) void k2(const ushort* __restrict__ hB,
                                          const ushort* __restrict__ Wt,
                                          const float* __restrict__ bA,
                                          const float* __restrict__ bF,
                                          float* __restrict__ Lbar,
                                          float* __restrict__ SnegP,
                                          float* __restrict__ lgF) {
    const int ct = blockIdx.x;   // 0..21
    const int rt = blockIdx.y;   // 0..15
    const int t = threadIdx.x;
    const int w = t >> 6, lane = t & 63;
    const int wm = w >> 1, wn = w & 1;
    const int quad = lane >> 4, l16 = lane & 15;
    floatx4 acc[2][2] = {};
    const int row0 = rt * 64, col0 = ct * 64;

    const ushort* ga0 = hB + (row0 + wm * 32 + l16) * 1024 + quad * 8;
    const ushort* ga1 = ga0 + 16 * 1024;
    const ushort* gb0 = Wt + (col0 + wn * 32 + l16) * 1024 + quad * 8;
    const ushort* gb1 = gb0 + 16 * 1024;

    // Two named frag buffers, 8 frags each (kk0/kk1 x {a0,a1,b0,b1}).
    short8 p0a0, p0a1, p0b0, p0b1, p0c0, p0c1, p0d0, p0d1;
    short8 p1a0, p1a1, p1b0, p1b1, p1c0, p1c1, p1d0, p1d1;

#define LD0(off) { p0a0 = *(const short8*)(ga0 + (off));      p0b0 = *(const short8*)(ga1 + (off)); \
                   p0c0 = *(const short8*)(gb0 + (off));      p0d0 = *(const short8*)(gb1 + (off)); \
                   p0a1 = *(const short8*)(ga0 + (off) + 32); p0b1 = *(const short8*)(ga1 + (off) + 32); \
                   p0c1 = *(const short8*)(gb0 + (off) + 32); p0d1 = *(const short8*)(gb1 + (off) + 32); }
#define LD1(off) { p1a0 = *(const short8*)(ga0 + (off));      p1b0 = *(const short8*)(ga1 + (off)); \
                   p1c0 = *(const short8*)(gb0 + (off));      p1d0 = *(const short8*)(gb1 + (off)); \
                   p1a1 = *(const short8*)(ga0 + (off) + 32); p1b1 = *(const short8*)(ga1 + (off) + 32); \
                   p1c1 = *(const short8*)(gb0 + (off) + 32); p1d1 = *(const short8*)(gb1 + (off) + 32); }
#define MFMA0() { acc[0][0] = __builtin_amdgcn_mfma_f32_16x16x32_bf16(p0a0, p0c0, acc[0][0], 0, 0, 0); \
                  acc[0][1] = __builtin_amdgcn_mfma_f32_16x16x32_bf16(p0a0, p0d0, acc[0][1], 0, 0, 0); \
                  acc[1][0] = __builtin_amdgcn_mfma_f32_16x16x32_bf16(p0b0, p0c0, acc[1][0], 0, 0, 0); \
                  acc[1][1] = __builtin_amdgcn_mfma_f32_16x16x32_bf16(p0b0, p0d0, acc[1][1], 0, 0, 0); \
                  acc[0][0] = __builtin_amdgcn_mfma_f32_16x16x32_bf16(p0a1, p0c1, acc[0][0], 0, 0, 0); \
                  acc[0][1] = __builtin_amdgcn_mfma_f32_16x16x32_bf16(p0a1, p0d1, acc[0][1], 0, 0, 0); \
                  acc[1][0] = __builtin_amdgcn_mfma_f32_16x16x32_bf16(p0b1, p0c1, acc[1][0], 0, 0, 0); \
                  acc[1][1] = __builtin_amdgcn_mfma_f32_16x16x32_bf16(p0b1, p0d1, acc[1][1], 0, 0, 0); }
#define MFMA1() { acc[0][0] = __builtin_amdgcn_mfma_f32_16x16x32_bf16(p1a0, p1c0, acc[0][0], 0, 0, 0); \
                  acc[0][1] = __builtin_amdgcn_mfma_f32_16x16x32_bf16(p1a0, p1d0, acc[0][1], 0, 0, 0); \
                  acc[1][0] = __builtin_amdgcn_mfma_f32_16x16x32_bf16(p1b0, p1c0, acc[1][0], 0, 0, 0); \
                  acc[1][1] = __builtin_amdgcn_mfma_f32_16x16x32_bf16(p1b0, p1d0, acc[1][1], 0, 0, 0); \
                  acc[0][0] = __builtin_amdgcn_mfma_f32_16x16x32_bf16(p1a1, p1c1, acc[0][0], 0, 0, 0); \
                  acc[0][1] = __builtin_amdgcn_mfma_f32_16x16x32_bf16(p1a1, p1d1, acc[0][1], 0, 0, 0); \
                  acc[1][0] = __builtin_amdgcn_mfma_f32_16x16x32_bf16(p1b1, p1c1, acc[1][0], 0, 0, 0); \
                  acc[1][1] = __builtin_amdgcn_mfma_f32_16x16x32_bf16(p1b1, p1d1, acc[1][1], 0, 0, 0); }

    LD0(0)
    #pragma unroll
    for (int ch = 0; ch < 16; ch += 2) {
        LD1((ch + 1) * 64)
        MFMA0()
        if (ch + 2 < 16) LD0((ch + 2) * 64)
        MFMA1()
    }
#undef LD0
#undef LD1
#undef MFMA0
#undef MFMA1

    // Epilogue: C/D layout col=lane&15, row=quad*4+reg -> lane's 4 regs = graph b, m=0..3
    #pragma unroll
    for (int mi = 0; mi < 2; mi++) {
        const int grow = row0 + wm * 32 + mi * 16 + quad * 4;
        const int b = grow >> 2;
        float sn0 = 0.f, sn1 = 0.f, sn2 = 0.f, sn3 = 0.f;
        #pragma unroll
        for (int ni = 0; ni < 2; ni++) {
            int gc = col0 + wn * 32 + ni * 16 + l16;
            floatx4 a = acc[mi][ni];
            if (gc < EE) {
                float bias = bA[gc];
                float l0 = a[0] + bias, l1 = a[1] + bias, l2 = a[2] + bias, l3 = a[3] + bias;
                Lbar[b * EE + gc] = 0.25f * (l0 + l1 + l2 + l3);
                sn0 += logsigm(l0); sn1 += logsigm(l1); sn2 += logsigm(l2); sn3 += logsigm(l3);
            } else if (gc < CTOT) {
                int c2 = gc - EE;
                float bias = bF[c2];
                lgF[(b * 4 + 0) * 150 + c2] = a[0] + bias;
                lgF[(b * 4 + 1) * 150 + c2] = a[1] + bias;
                lgF[(b * 4 + 2) * 150 + c2] = a[2] + bias;
                lgF[(b * 4 + 3) * 150 + c2] = a[3] + bias;
            }
        }
        #pragma unroll
        for (int msk = 1; msk < 16; msk <<= 1) {
            sn0 += __shfl_xor(sn0, msk);
            sn1 += __shfl_xor(sn1, msk);
            sn2 += __shfl_xor(sn2, msk);
            sn3 += __shfl_xor(sn3, msk);
        }
        if (l16 == 0) {
            const int o = ct * 2 + wn;
            SnegP[(b * 4 + 0) * 44 + o] = sn0;
            SnegP[(b * 4 + 1) * 44 + o] = sn1;
            SnegP[(b * 4 + 2) * 44 + o] = sn2;
            SnegP[(b * 4 + 3) * 44 + o] = sn3;
        }
    }
}

// K4: per-graph finalization. grid 256, 512 threads (8 waves).
// lane = permutation (64 lanes = 64 perms), wave = edge-stripe (8-way).
// Also reduces the 44 SnegP partials per (b,m) (no global atomics anywhere).
__global__ __launch_bounds__(512) void k4(const float* __restrict__ Fx,
                                          const float* __restrict__ coeff,
                                          const int* __restrict__ ipG,
                                          const float* __restrict__ Lbar,
                                          const float* __restrict__ SnegP,
                                          const float* __restrict__ lgF,
                                          const int* __restrict__ edgesG,
                                          const int* __restrict__ cntG,
                                          const float* __restrict__ kldG,
                                          float* __restrict__ out) {
    const int b = blockIdx.x;
    const int t = threadIdx.x;
    const int w = t >> 6, lane = t & 63;
    __shared__ int   ip[PP * 51];      // [perm][node], stride 51 (odd -> 2-way banks)
    __shared__ float LbF[NN * 51];     // full symmetric matrix
    __shared__ int   edges[256];
    __shared__ float lgfs[600];
    __shared__ float mred[4], snegR[4];
    __shared__ float psum[8][64];

    const int ne = cntG[b];
    for (int x = t; x < PP * 51; x += 512) ip[x] = ipG[x];
    for (int x = t; x < 2500; x += 512) {
        int i = x / NN, j = x - i * NN;
        if (j < i) {
            float v = Lbar[b * EE + i * (i - 1) / 2 + j];
            LbF[i * 51 + j] = v;
            LbF[j * 51 + i] = v;
        }
    }
    for (int x = t; x < 600; x += 512) lgfs[x] = lgF[b * 600 + x];
    if (t < ne) edges[t] = edgesG[b * 256 + t];
    __syncthreads();

    // perm partial sums: all 64 perms in flight per wave, edges striped by wave
    {
        const int ipB = lane * 51;
        float acc = 0.f;
        for (int x = w; x < ne; x += 8) {
            int ed = edges[x];
            int iu = ip[ipB + (ed >> 8)];
            int iv = ip[ipB + (ed & 255)];
            acc += LbF[iu * 51 + iv];
        }
        psum[w][lane] = acc;
    }

    // Fx terms + Sneg partial reduce: waves 0..3 handle sample m = w
    if (w < 4) {
        float l0 = 0.f, l1 = 0.f, l2 = -INFINITY, x0 = 0.f, x1 = 0.f, x2 = 0.f;
        bool v = lane < NN;
        if (v) {
            l0 = lgfs[w * 150 + lane * 3 + 0];
            l1 = lgfs[w * 150 + lane * 3 + 1];
            l2 = lgfs[w * 150 + lane * 3 + 2];
            x0 = Fx[b * 150 + lane * 3 + 0];
            x1 = Fx[b * 150 + lane * 3 + 1];
            x2 = Fx[b * 150 + lane * 3 + 2];
        }
        float mx = wmax64(l2);
        float es = v ? expf(l2 - mx) : 0.f;
        es = wsum64(es);
        float lse = mx + logf(es);
        float val = 0.f;
        if (v) {
            val = coeff[0] * (logsigm(l0) + x0 * l0)
                + coeff[1] * (logsigm(l1) + x1 * l1)
                + coeff[2] * (x2 * (l2 - lse));
        }
        val = wsum64(val);
        float sv = (lane < 44) ? SnegP[(b * 4 + w) * 44 + lane] : 0.f;
        sv = wsum64(sv);
        if (lane == 0) { mred[w] = val; snegR[w] = sv; }
    }
    __syncthreads();

    if (w == 0) {
        float s = psum[0][lane];
        #pragma unroll
        for (int i = 1; i < 8; i++) s += psum[i][lane];
        float dmax = wmax64(s);
        if (lane == 0) {
            float sbar = 0.25f * (snegR[0] + snegR[1] + snegR[2] + snegR[3]);
            float fxv  = 0.25f * (mred[0] + mred[1] + mred[2] + mred[3]);
            out[b] = (sbar + dmax) + fxv - kldG[b];
        }
    }
}

extern "C" void kernel_launch(void* const* d_in, const int* in_sizes, int n_in,
                              void* d_out, int out_size, void* d_ws, size_t ws_size,
                              hipStream_t stream) {
    const float* mean   = (const float*)d_in[0];
    const float* logvar = (const float*)d_in[1];
    const float* eps    = (const float*)d_in[2];
    const float* W1     = (const float*)d_in[3];
    const float* b1     = (const float*)d_in[4];
    const float* WA     = (const float*)d_in[5];
    const float* bA     = (const float*)d_in[6];
    const float* WF     = (const float*)d_in[7];
    const float* bF     = (const float*)d_in[8];
    const float* A      = (const float*)d_in[9];
    const float* Fx     = (const float*)d_in[10];
    const float* coeff  = (const float*)d_in[11];
    const int*   perms  = (const int*)d_in[12];
    float* out = (float*)d_out;

    ushort* Wt   = (ushort*)d_ws;               // 1408*1024 bf16
    ushort* hB   = Wt + NPAD * 1024;            // 1024*1024 bf16
    float*  Lbar = (float*)(hB + 1024 * 1024);  // 256*1225
    float*  SnegP = Lbar + BB * EE;             // 256*4*44 partials (written by k2)
    float*  lgF  = SnegP + 256 * 4 * 44;        // 1024*150
    int*    edgesG = (int*)(lgF + 1024 * 150);  // 256*256
    int*    cntG   = edgesG + 256 * 256;        // 256
    float*  kldG   = (float*)(cntG + 256);      // 256
    int*    ipG    = (int*)(kldG + 256);        // 64*51

    kA<<<dim3(612), dim3(256), 0, stream>>>(mean, logvar, eps, W1, b1, WA, WF, A, perms,
                                            hB, Wt, edgesG, cntG, kldG, ipG);
    k2<<<dim3(22, 16), dim3(256), 0, stream>>>(hB, Wt, bA, bF, Lbar, SnegP, lgF);
    k4<<<dim3(BB), dim3(512), 0, stream>>>(Fx, coeff, ipG, Lbar, SnegP, lgF,
                                           edgesG, cntG, kldG, out);
}

// Round 6
// 123.762 us; speedup vs baseline: 1.5242x; 1.1430x over previous
//
#include <hip/hip_runtime.h>
#include <math.h>

// Problem constants
#define MM 4
#define BB 256
#define KK 64
#define HH 1024
#define NN 50
#define EE 1225
#define PP 64
#define CTOT 1375   // E + N*3
#define NPAD 1408   // cols padded to 22*64

// History: R3 5x-launch: t_k2+gap ~ 15.8 us. R5 direct-from-L2 k2 REGRESSED
// +16 us (scattered 64B fragment loads serialize at the TA; LDS staging's
// coalesced 128B lines are the win, not a cost). R6: revert k2 to the R2
// ping-pong LDS structure (best known), keep SnegP plain stores + ipG + k4.

typedef short short8 __attribute__((ext_vector_type(8)));
typedef float floatx4 __attribute__((ext_vector_type(4)));
typedef unsigned short ushort;

__device__ __forceinline__ ushort f2bf(float f) {
    union { float f; unsigned u; } v; v.f = f;
    unsigned r = v.u + 0x7fffu + ((v.u >> 16) & 1u);
    return (ushort)(r >> 16);
}

__device__ __forceinline__ float logsigm(float l) {
    // log sigmoid(-l) = -(max(l,0) + log1p(exp(-|l|)))
    return -(fmaxf(l, 0.0f) + log1pf(expf(-fabsf(l))));
}

__device__ __forceinline__ float wsum64(float v) {
    #pragma unroll
    for (int m = 1; m < 64; m <<= 1) v += __shfl_xor(v, m);
    return v;
}
__device__ __forceinline__ float wmax64(float v) {
    #pragma unroll
    for (int m = 1; m < 64; m <<= 1) v = fmaxf(v, __shfl_xor(v, m));
    return v;
}

// kA: fused weight transpose (blocks 256..607) + per-graph work (blocks 0..255)
// + perm-inverse table build (blocks 608..611, graph-independent, feeds k4).
// NOTE (prior session): keep a plain 3-kernel chain. Cooperative grid-sync
// fusion cost +78 us; atomic producer-consumer +46 us.
__global__ __launch_bounds__(256) void kA(const float* __restrict__ mean,
                                          const float* __restrict__ logvar,
                                          const float* __restrict__ eps,
                                          const float* __restrict__ W1,
                                          const float* __restrict__ b1,
                                          const float* __restrict__ WA,
                                          const float* __restrict__ WF,
                                          const float* __restrict__ A,
                                          const int*   __restrict__ perms,
                                          ushort* __restrict__ hB,
                                          ushort* __restrict__ Wt,
                                          int*   __restrict__ edgesG,
                                          int*   __restrict__ cntG,
                                          float* __restrict__ kldG,
                                          int*   __restrict__ ipG) {
    const int t = threadIdx.x;
    __shared__ float smem[64 * 65];
    __shared__ int cnt;

    if (blockIdx.x < 256) {
        // ---- per-graph block ----
        const int b = blockIdx.x;
        float4* z4 = (float4*)smem;
        if (t == 0) cnt = 0;
        if (t < 64) {
            float mv = mean[b * 64 + t];
            float lv = logvar[b * 64 + t];
            float sd = expf(0.5f * lv);
            float4 z;
            z.x = mv + sd * eps[(0 * BB + b) * 64 + t];
            z.y = mv + sd * eps[(1 * BB + b) * 64 + t];
            z.z = mv + sd * eps[(2 * BB + b) * 64 + t];
            z.w = mv + sd * eps[(3 * BB + b) * 64 + t];
            z4[t] = z;
            // KLD (wave 0, one lane per latent dim)
            float term = 0.5f * (expf(lv) + mv * mv - 1.0f - lv);
            term = wsum64(term);
            if (t == 0) kldG[b] = term;
        }
        __syncthreads();
        const int j0 = t * 4;
        float acc[4][4] = {};   // [m][jc]
        #pragma unroll 8
        for (int k = 0; k < 64; k++) {
            float4 w = *(const float4*)&W1[k * HH + j0];
            float4 z = z4[k];
            acc[0][0] += z.x * w.x; acc[0][1] += z.x * w.y; acc[0][2] += z.x * w.z; acc[0][3] += z.x * w.w;
            acc[1][0] += z.y * w.x; acc[1][1] += z.y * w.y; acc[1][2] += z.y * w.z; acc[1][3] += z.y * w.w;
            acc[2][0] += z.z * w.x; acc[2][1] += z.z * w.y; acc[2][2] += z.z * w.z; acc[2][3] += z.z * w.w;
            acc[3][0] += z.w * w.x; acc[3][1] += z.w * w.y; acc[3][2] += z.w * w.z; acc[3][3] += z.w * w.w;
        }
        float4 bb = *(const float4*)&b1[j0];
        #pragma unroll
        for (int m = 0; m < 4; m++) {
            unsigned u0 = ((unsigned)f2bf(fmaxf(acc[m][0] + bb.x, 0.f))) |
                          ((unsigned)f2bf(fmaxf(acc[m][1] + bb.y, 0.f)) << 16);
            unsigned u1 = ((unsigned)f2bf(fmaxf(acc[m][2] + bb.z, 0.f))) |
                          ((unsigned)f2bf(fmaxf(acc[m][3] + bb.w, 0.f)) << 16);
            uint2 u; u.x = u0; u.y = u1;
            *(uint2*)&hB[(b * 4 + m) * HH + j0] = u;
        }
        // ---- edge extraction: coalesced scan of A[b], lower triangle ----
        for (int x = t; x < 2500; x += 256) {
            int i = x / NN, j = x - i * NN;
            if (j < i) {
                float a = A[b * 2500 + x];
                if (a != 0.0f) { int id = atomicAdd(&cnt, 1); edgesG[b * 256 + id] = (i << 8) | j; }
            }
        }
        __syncthreads();
        if (t == 0) cntG[b] = cnt;
    } else if (blockIdx.x < 608) {
        // ---- Wt[n][k] = transpose of [WA | WF] (bf16, zero-padded cols) ----
        const int id = blockIdx.x - 256;
        const int kt = id & 15, nt = id >> 4;
        float* T = smem;   // [64][65]
        const int k0 = kt * 64, n0 = nt * 64;
        #pragma unroll
        for (int i = 0; i < 16; i++) {
            int x = i * 256 + t;
            int kk = x >> 6, nn = x & 63;
            int gn = n0 + nn, gk = k0 + kk;
            float v = 0.f;
            if (gn < EE)        v = WA[gk * EE + gn];
            else if (gn < CTOT) v = WF[gk * 150 + (gn - EE)];
            T[kk * 65 + nn] = v;
        }
        __syncthreads();
        #pragma unroll
        for (int i = 0; i < 16; i++) {
            int x = i * 256 + t;
            int nn = x >> 6, kk = x & 63;
            Wt[(n0 + nn) * 1024 + k0 + kk] = f2bf(T[kk * 65 + nn]);
        }
    } else {
        // ---- ipG[p][node] = position of node in perm p (stride 51, b-independent) ----
        const int id = blockIdx.x - 608;   // 0..3, 16 perms each
        for (int x = id * 800 + t; x < (id + 1) * 800; x += 256) {
            int p = x / NN, i = x - p * NN;
            ipG[p * 51 + perms[x]] = i;
        }
    }
}

// K2: MFMA GEMM logits[1024][1375] = hB @ Wt^T with fused epilogue.
// R6 = R2 structure (best measured): double-buffered LDS ping-pong, one
// barrier per K-chunk, coalesced short8 staging (8 threads/row -> full
// 128B lines), register prefetch one chunk ahead. SnegP plain stores.
// 64x64 tile, grid 22x16 = 352 blocks, 4 waves (2x2), wave 32x32. LDS 36.9KB.
__global__ __launch_bounds__(256) void k2(const ushort* __restrict__ hB,
                                          const ushort* __restrict__ Wt,
                                          const float* __restrict__ bA,
                                          const float* __restrict__ bF,
                                          float* __restrict__ Lbar,
                                          float* __restrict__ SnegP,
                                          float* __restrict__ lgF) {
    const int ct = blockIdx.x;   // 0..21
    const int rt = blockIdx.y;   // 0..15
    const int t = threadIdx.x;
    const int w = t >> 6, lane = t & 63;
    const int wm = w >> 1, wn = w & 1;
    const int quad = lane >> 4, l16 = lane & 15;
    __shared__ short As[2][64][72];
    __shared__ short Bs[2][64][72];
    floatx4 acc[2][2] = {};
    const int row0 = rt * 64, col0 = ct * 64;

    const int r0 = t >> 3, koA = (t & 7) * 8;
    const int r1 = r0 + 32;
    const ushort* pA0 = hB + (row0 + r0) * 1024 + koA;
    const ushort* pA1 = hB + (row0 + r1) * 1024 + koA;
    const ushort* pB0 = Wt + (col0 + r0) * 1024 + koA;
    const ushort* pB1 = Wt + (col0 + r1) * 1024 + koA;

    short8 ra0 = *(const short8*)(pA0);
    short8 ra1 = *(const short8*)(pA1);
    short8 rb0 = *(const short8*)(pB0);
    short8 rb1 = *(const short8*)(pB1);
    *(short8*)&As[0][r0][koA] = ra0;
    *(short8*)&As[0][r1][koA] = ra1;
    *(short8*)&Bs[0][r0][koA] = rb0;
    *(short8*)&Bs[0][r1][koA] = rb1;
    __syncthreads();

    int cur = 0;
    for (int ch = 0; ch < 16; ch++) {
        if (ch < 15) {
            const int off = (ch + 1) * 64;
            ra0 = *(const short8*)(pA0 + off);
            ra1 = *(const short8*)(pA1 + off);
            rb0 = *(const short8*)(pB0 + off);
            rb1 = *(const short8*)(pB1 + off);
        }
        #pragma unroll
        for (int kk = 0; kk < 2; kk++) {
            int ko = kk * 32 + quad * 8;
            short8 a0 = *(const short8*)&As[cur][wm * 32 + l16][ko];
            short8 a1 = *(const short8*)&As[cur][wm * 32 + 16 + l16][ko];
            short8 b0 = *(const short8*)&Bs[cur][wn * 32 + l16][ko];
            short8 b1 = *(const short8*)&Bs[cur][wn * 32 + 16 + l16][ko];
            acc[0][0] = __builtin_amdgcn_mfma_f32_16x16x32_bf16(a0, b0, acc[0][0], 0, 0, 0);
            acc[0][1] = __builtin_amdgcn_mfma_f32_16x16x32_bf16(a0, b1, acc[0][1], 0, 0, 0);
            acc[1][0] = __builtin_amdgcn_mfma_f32_16x16x32_bf16(a1, b0, acc[1][0], 0, 0, 0);
            acc[1][1] = __builtin_amdgcn_mfma_f32_16x16x32_bf16(a1, b1, acc[1][1], 0, 0, 0);
        }
        if (ch < 15) {
            *(short8*)&As[cur ^ 1][r0][koA] = ra0;
            *(short8*)&As[cur ^ 1][r1][koA] = ra1;
            *(short8*)&Bs[cur ^ 1][r0][koA] = rb0;
            *(short8*)&Bs[cur ^ 1][r1][koA] = rb1;
            __syncthreads();
            cur ^= 1;
        }
    }

    // Epilogue: C/D layout col=lane&15, row=quad*4+reg -> lane's 4 regs = graph b, m=0..3
    #pragma unroll
    for (int mi = 0; mi < 2; mi++) {
        const int grow = row0 + wm * 32 + mi * 16 + quad * 4;
        const int b = grow >> 2;
        float sn0 = 0.f, sn1 = 0.f, sn2 = 0.f, sn3 = 0.f;
        #pragma unroll
        for (int ni = 0; ni < 2; ni++) {
            int gc = col0 + wn * 32 + ni * 16 + l16;
            floatx4 a = acc[mi][ni];
            if (gc < EE) {
                float bias = bA[gc];
                float l0 = a[0] + bias, l1 = a[1] + bias, l2 = a[2] + bias, l3 = a[3] + bias;
                Lbar[b * EE + gc] = 0.25f * (l0 + l1 + l2 + l3);
                sn0 += logsigm(l0); sn1 += logsigm(l1); sn2 += logsigm(l2); sn3 += logsigm(l3);
            } else if (gc < CTOT) {
                int c2 = gc - EE;
                float bias = bF[c2];
                lgF[(b * 4 + 0) * 150 + c2] = a[0] + bias;
                lgF[(b * 4 + 1) * 150 + c2] = a[1] + bias;
                lgF[(b * 4 + 2) * 150 + c2] = a[2] + bias;
                lgF[(b * 4 + 3) * 150 + c2] = a[3] + bias;
            }
        }
        #pragma unroll
        for (int msk = 1; msk < 16; msk <<= 1) {
            sn0 += __shfl_xor(sn0, msk);
            sn1 += __shfl_xor(sn1, msk);
            sn2 += __shfl_xor(sn2, msk);
            sn3 += __shfl_xor(sn3, msk);
        }
        if (l16 == 0) {
            const int o = ct * 2 + wn;
            SnegP[(b * 4 + 0) * 44 + o] = sn0;
            SnegP[(b * 4 + 1) * 44 + o] = sn1;
            SnegP[(b * 4 + 2) * 44 + o] = sn2;
            SnegP[(b * 4 + 3) * 44 + o] = sn3;
        }
    }
}

// K4: per-graph finalization. grid 256, 512 threads (8 waves).
// lane = permutation (64 lanes = 64 perms), wave = edge-stripe (8-way).
// Also reduces the 44 SnegP partials per (b,m) (no global atomics anywhere).
__global__ __launch_bounds__(512) void k4(const float* __restrict__ Fx,
                                          const float* __restrict__ coeff,
                                          const int* __restrict__ ipG,
                                          const float* __restrict__ Lbar,
                                          const float* __restrict__ SnegP,
                                          const float* __restrict__ lgF,
                                          const int* __restrict__ edgesG,
                                          const int* __restrict__ cntG,
                                          const float* __restrict__ kldG,
                                          float* __restrict__ out) {
    const int b = blockIdx.x;
    const int t = threadIdx.x;
    const int w = t >> 6, lane = t & 63;
    __shared__ int   ip[PP * 51];      // [perm][node], stride 51 (odd -> 2-way banks)
    __shared__ float LbF[NN * 51];     // full symmetric matrix
    __shared__ int   edges[256];
    __shared__ float lgfs[600];
    __shared__ float mred[4], snegR[4];
    __shared__ float psum[8][64];

    const int ne = cntG[b];
    for (int x = t; x < PP * 51; x += 512) ip[x] = ipG[x];
    for (int x = t; x < 2500; x += 512) {
        int i = x / NN, j = x - i * NN;
        if (j < i) {
            float v = Lbar[b * EE + i * (i - 1) / 2 + j];
            LbF[i * 51 + j] = v;
            LbF[j * 51 + i] = v;
        }
    }
    for (int x = t; x < 600; x += 512) lgfs[x] = lgF[b * 600 + x];
    if (t < ne) edges[t] = edgesG[b * 256 + t];
    __syncthreads();

    // perm partial sums: all 64 perms in flight per wave, edges striped by wave
    {
        const int ipB = lane * 51;
        float acc = 0.f;
        for (int x = w; x < ne; x += 8) {
            int ed = edges[x];
            int iu = ip[ipB + (ed >> 8)];
            int iv = ip[ipB + (ed & 255)];
            acc += LbF[iu * 51 + iv];
        }
        psum[w][lane] = acc;
    }

    // Fx terms + Sneg partial reduce: waves 0..3 handle sample m = w
    if (w < 4) {
        float l0 = 0.f, l1 = 0.f, l2 = -INFINITY, x0 = 0.f, x1 = 0.f, x2 = 0.f;
        bool v = lane < NN;
        if (v) {
            l0 = lgfs[w * 150 + lane * 3 + 0];
            l1 = lgfs[w * 150 + lane * 3 + 1];
            l2 = lgfs[w * 150 + lane * 3 + 2];
            x0 = Fx[b * 150 + lane * 3 + 0];
            x1 = Fx[b * 150 + lane * 3 + 1];
            x2 = Fx[b * 150 + lane * 3 + 2];
        }
        float mx = wmax64(l2);
        float es = v ? expf(l2 - mx) : 0.f;
        es = wsum64(es);
        float lse = mx + logf(es);
        float val = 0.f;
        if (v) {
            val = coeff[0] * (logsigm(l0) + x0 * l0)
                + coeff[1] * (logsigm(l1) + x1 * l1)
                + coeff[2] * (x2 * (l2 - lse));
        }
        val = wsum64(val);
        float sv = (lane < 44) ? SnegP[(b * 4 + w) * 44 + lane] : 0.f;
        sv = wsum64(sv);
        if (lane == 0) { mred[w] = val; snegR[w] = sv; }
    }
    __syncthreads();

    if (w == 0) {
        float s = psum[0][lane];
        #pragma unroll
        for (int i = 1; i < 8; i++) s += psum[i][lane];
        float dmax = wmax64(s);
        if (lane == 0) {
            float sbar = 0.25f * (snegR[0] + snegR[1] + snegR[2] + snegR[3]);
            float fxv  = 0.25f * (mred[0] + mred[1] + mred[2] + mred[3]);
            out[b] = (sbar + dmax) + fxv - kldG[b];
        }
    }
}

extern "C" void kernel_launch(void* const* d_in, const int* in_sizes, int n_in,
                              void* d_out, int out_size, void* d_ws, size_t ws_size,
                              hipStream_t stream) {
    const float* mean   = (const float*)d_in[0];
    const float* logvar = (const float*)d_in[1];
    const float* eps    = (const float*)d_in[2];
    const float* W1     = (const float*)d_in[3];
    const float* b1     = (const float*)d_in[4];
    const float* WA     = (const float*)d_in[5];
    const float* bA     = (const float*)d_in[6];
    const float* WF     = (const float*)d_in[7];
    const float* bF     = (const float*)d_in[8];
    const float* A      = (const float*)d_in[9];
    const float* Fx     = (const float*)d_in[10];
    const float* coeff  = (const float*)d_in[11];
    const int*   perms  = (const int*)d_in[12];
    float* out = (float*)d_out;

    ushort* Wt   = (ushort*)d_ws;               // 1408*1024 bf16
    ushort* hB   = Wt + NPAD * 1024;            // 1024*1024 bf16
    float*  Lbar = (float*)(hB + 1024 * 1024);  // 256*1225
    float*  SnegP = Lbar + BB * EE;             // 256*4*44 partials (written by k2)
    float*  lgF  = SnegP + 256 * 4 * 44;        // 1024*150
    int*    edgesG = (int*)(lgF + 1024 * 150);  // 256*256
    int*    cntG   = edgesG + 256 * 256;        // 256
    float*  kldG   = (float*)(cntG + 256);      // 256
    int*    ipG    = (int*)(kldG + 256);        // 64*51

    kA<<<dim3(612), dim3(256), 0, stream>>>(mean, logvar, eps, W1, b1, WA, WF, A, perms,
                                            hB, Wt, edgesG, cntG, kldG, ipG);
    k2<<<dim3(22, 16), dim3(256), 0, stream>>>(hB, Wt, bA, bF, Lbar, SnegP, lgF);
    k4<<<dim3(BB), dim3(512), 0, stream>>>(Fx, coeff, ipG, Lbar, SnegP, lgF,
                                           edgesG, cntG, kldG, out);
}

// Round 7
// 120.094 us; speedup vs baseline: 1.5707x; 1.0305x over previous
//
#include <hip/hip_runtime.h>
#include <math.h>

// Problem constants
#define MM 4
#define BB 256
#define KK 64
#define HH 1024
#define NN 50
#define EE 1225
#define PP 64
#define CTOT 1375   // E + N*3
#define NPAD 1408   // cols padded to 22*64

// History: R3 5x-launch: t_k2+gap ~ 15.8 us -> k2 ~ 12-13 us. R5 no-LDS k2
// regressed +16 us (uncoalesced fragment loads). R6 revert = 123.8 us (best).
// R7: k2 2-chunk-deep register prefetch — loads for ch+2 issued at compute(ch),
// consumed (ds_write) after MFMA(ch+1): ~1 full chunk (~800cy) of latency
// cover vs ~300cy before. Targets the L3-hit latency (hB/Wt written by other
// XCDs) that the 1-deep pipeline exposed at every chunk's vmcnt wait.

typedef short short8 __attribute__((ext_vector_type(8)));
typedef float floatx4 __attribute__((ext_vector_type(4)));
typedef unsigned short ushort;

__device__ __forceinline__ ushort f2bf(float f) {
    union { float f; unsigned u; } v; v.f = f;
    unsigned r = v.u + 0x7fffu + ((v.u >> 16) & 1u);
    return (ushort)(r >> 16);
}

__device__ __forceinline__ float logsigm(float l) {
    // log sigmoid(-l) = -(max(l,0) + log1p(exp(-|l|)))
    return -(fmaxf(l, 0.0f) + log1pf(expf(-fabsf(l))));
}

__device__ __forceinline__ float wsum64(float v) {
    #pragma unroll
    for (int m = 1; m < 64; m <<= 1) v += __shfl_xor(v, m);
    return v;
}
__device__ __forceinline__ float wmax64(float v) {
    #pragma unroll
    for (int m = 1; m < 64; m <<= 1) v = fmaxf(v, __shfl_xor(v, m));
    return v;
}

// kA: fused weight transpose (blocks 256..607) + per-graph work (blocks 0..255)
// + perm-inverse table build (blocks 608..611, graph-independent, feeds k4).
// NOTE (prior session): keep a plain 3-kernel chain. Cooperative grid-sync
// fusion cost +78 us; atomic producer-consumer +46 us.
__global__ __launch_bounds__(256) void kA(const float* __restrict__ mean,
                                          const float* __restrict__ logvar,
                                          const float* __restrict__ eps,
                                          const float* __restrict__ W1,
                                          const float* __restrict__ b1,
                                          const float* __restrict__ WA,
                                          const float* __restrict__ WF,
                                          const float* __restrict__ A,
                                          const int*   __restrict__ perms,
                                          ushort* __restrict__ hB,
                                          ushort* __restrict__ Wt,
                                          int*   __restrict__ edgesG,
                                          int*   __restrict__ cntG,
                                          float* __restrict__ kldG,
                                          int*   __restrict__ ipG) {
    const int t = threadIdx.x;
    __shared__ float smem[64 * 65];
    __shared__ int cnt;

    if (blockIdx.x < 256) {
        // ---- per-graph block ----
        const int b = blockIdx.x;
        float4* z4 = (float4*)smem;
        if (t == 0) cnt = 0;
        if (t < 64) {
            float mv = mean[b * 64 + t];
            float lv = logvar[b * 64 + t];
            float sd = expf(0.5f * lv);
            float4 z;
            z.x = mv + sd * eps[(0 * BB + b) * 64 + t];
            z.y = mv + sd * eps[(1 * BB + b) * 64 + t];
            z.z = mv + sd * eps[(2 * BB + b) * 64 + t];
            z.w = mv + sd * eps[(3 * BB + b) * 64 + t];
            z4[t] = z;
            // KLD (wave 0, one lane per latent dim)
            float term = 0.5f * (expf(lv) + mv * mv - 1.0f - lv);
            term = wsum64(term);
            if (t == 0) kldG[b] = term;
        }
        __syncthreads();
        const int j0 = t * 4;
        float acc[4][4] = {};   // [m][jc]
        #pragma unroll 8
        for (int k = 0; k < 64; k++) {
            float4 w = *(const float4*)&W1[k * HH + j0];
            float4 z = z4[k];
            acc[0][0] += z.x * w.x; acc[0][1] += z.x * w.y; acc[0][2] += z.x * w.z; acc[0][3] += z.x * w.w;
            acc[1][0] += z.y * w.x; acc[1][1] += z.y * w.y; acc[1][2] += z.y * w.z; acc[1][3] += z.y * w.w;
            acc[2][0] += z.z * w.x; acc[2][1] += z.z * w.y; acc[2][2] += z.z * w.z; acc[2][3] += z.z * w.w;
            acc[3][0] += z.w * w.x; acc[3][1] += z.w * w.y; acc[3][2] += z.w * w.z; acc[3][3] += z.w * w.w;
        }
        float4 bb = *(const float4*)&b1[j0];
        #pragma unroll
        for (int m = 0; m < 4; m++) {
            unsigned u0 = ((unsigned)f2bf(fmaxf(acc[m][0] + bb.x, 0.f))) |
                          ((unsigned)f2bf(fmaxf(acc[m][1] + bb.y, 0.f)) << 16);
            unsigned u1 = ((unsigned)f2bf(fmaxf(acc[m][2] + bb.z, 0.f))) |
                          ((unsigned)f2bf(fmaxf(acc[m][3] + bb.w, 0.f)) << 16);
            uint2 u; u.x = u0; u.y = u1;
            *(uint2*)&hB[(b * 4 + m) * HH + j0] = u;
        }
        // ---- edge extraction: coalesced scan of A[b], lower triangle ----
        for (int x = t; x < 2500; x += 256) {
            int i = x / NN, j = x - i * NN;
            if (j < i) {
                float a = A[b * 2500 + x];
                if (a != 0.0f) { int id = atomicAdd(&cnt, 1); edgesG[b * 256 + id] = (i << 8) | j; }
            }
        }
        __syncthreads();
        if (t == 0) cntG[b] = cnt;
    } else if (blockIdx.x < 608) {
        // ---- Wt[n][k] = transpose of [WA | WF] (bf16, zero-padded cols) ----
        const int id = blockIdx.x - 256;
        const int kt = id & 15, nt = id >> 4;
        float* T = smem;   // [64][65]
        const int k0 = kt * 64, n0 = nt * 64;
        #pragma unroll
        for (int i = 0; i < 16; i++) {
            int x = i * 256 + t;
            int kk = x >> 6, nn = x & 63;
            int gn = n0 + nn, gk = k0 + kk;
            float v = 0.f;
            if (gn < EE)        v = WA[gk * EE + gn];
            else if (gn < CTOT) v = WF[gk * 150 + (gn - EE)];
            T[kk * 65 + nn] = v;
        }
        __syncthreads();
        #pragma unroll
        for (int i = 0; i < 16; i++) {
            int x = i * 256 + t;
            int nn = x >> 6, kk = x & 63;
            Wt[(n0 + nn) * 1024 + k0 + kk] = f2bf(T[kk * 65 + nn]);
        }
    } else {
        // ---- ipG[p][node] = position of node in perm p (stride 51, b-independent) ----
        const int id = blockIdx.x - 608;   // 0..3, 16 perms each
        for (int x = id * 800 + t; x < (id + 1) * 800; x += 256) {
            int p = x / NN, i = x - p * NN;
            ipG[p * 51 + perms[x]] = i;
        }
    }
}

// K2: MFMA GEMM logits[1024][1375] = hB @ Wt^T with fused epilogue.
// R7: 2-chunk-deep register prefetch. Named sets R/S (static indexing, no
// scratch): at even chunk ch, issue S<-ch+2, MFMA(buf0), ds_write R(ch+1)
// ->buf1, barrier; at odd ch+1, issue R<-ch+3, MFMA(buf1), ds_write S->buf0.
// One barrier per chunk; load->ds_write distance = one full chunk (~800cy),
// covering cross-XCD L3 hit latency. Coalesced short8 staging retained.
// 64x64 tile, grid 22x16 = 352 blocks, 4 waves (2x2), wave 32x32. LDS 36.9KB.
__global__ __launch_bounds__(256) void k2(const ushort* __restrict__ hB,
                                          const ushort* __restrict__ Wt,
                                          const float* __restrict__ bA,
                                          const float* __restrict__ bF,
                                          float* __restrict__ Lbar,
                                          float* __restrict__ SnegP,
                                          float* __restrict__ lgF) {
    const int ct = blockIdx.x;   // 0..21
    const int rt = blockIdx.y;   // 0..15
    const int t = threadIdx.x;
    const int w = t >> 6, lane = t & 63;
    const int wm = w >> 1, wn = w & 1;
    const int quad = lane >> 4, l16 = lane & 15;
    __shared__ short As[2][64][72];
    __shared__ short Bs[2][64][72];
    floatx4 acc[2][2] = {};
    const int row0 = rt * 64, col0 = ct * 64;

    const int r0 = t >> 3, koA = (t & 7) * 8;
    const int r1 = r0 + 32;
    const ushort* pA0 = hB + (row0 + r0) * 1024 + koA;
    const ushort* pA1 = hB + (row0 + r1) * 1024 + koA;
    const ushort* pB0 = Wt + (col0 + r0) * 1024 + koA;
    const ushort* pB1 = Wt + (col0 + r1) * 1024 + koA;

    short8 ra0, ra1, rb0, rb1;   // set R: holds chunk ch+1 in flight
    short8 sa0, sa1, sb0, sb1;   // set S: holds chunk ch+2 in flight

#define MFMA_FROM(B) { \
        _Pragma("unroll") \
        for (int kk = 0; kk < 2; kk++) { \
            int ko = kk * 32 + quad * 8; \
            short8 a0 = *(const short8*)&As[B][wm * 32 + l16][ko]; \
            short8 a1 = *(const short8*)&As[B][wm * 32 + 16 + l16][ko]; \
            short8 b0 = *(const short8*)&Bs[B][wn * 32 + l16][ko]; \
            short8 b1 = *(const short8*)&Bs[B][wn * 32 + 16 + l16][ko]; \
            acc[0][0] = __builtin_amdgcn_mfma_f32_16x16x32_bf16(a0, b0, acc[0][0], 0, 0, 0); \
            acc[0][1] = __builtin_amdgcn_mfma_f32_16x16x32_bf16(a0, b1, acc[0][1], 0, 0, 0); \
            acc[1][0] = __builtin_amdgcn_mfma_f32_16x16x32_bf16(a1, b0, acc[1][0], 0, 0, 0); \
            acc[1][1] = __builtin_amdgcn_mfma_f32_16x16x32_bf16(a1, b1, acc[1][1], 0, 0, 0); \
        } }

    // Prologue: chunk 0 -> buf0; issue chunk 1 into R.
    ra0 = *(const short8*)(pA0);
    ra1 = *(const short8*)(pA1);
    rb0 = *(const short8*)(pB0);
    rb1 = *(const short8*)(pB1);
    *(short8*)&As[0][r0][koA] = ra0;
    *(short8*)&As[0][r1][koA] = ra1;
    *(short8*)&Bs[0][r0][koA] = rb0;
    *(short8*)&Bs[0][r1][koA] = rb1;
    ra0 = *(const short8*)(pA0 + 64);
    ra1 = *(const short8*)(pA1 + 64);
    rb0 = *(const short8*)(pB0 + 64);
    rb1 = *(const short8*)(pB1 + 64);
    __syncthreads();

    #pragma unroll
    for (int ch = 0; ch < 16; ch += 2) {
        // EVEN chunk ch: compute buf0; R holds ch+1; issue S <- ch+2.
        if (ch + 2 < 16) {
            const int off = (ch + 2) * 64;
            sa0 = *(const short8*)(pA0 + off);
            sa1 = *(const short8*)(pA1 + off);
            sb0 = *(const short8*)(pB0 + off);
            sb1 = *(const short8*)(pB1 + off);
        }
        MFMA_FROM(0)
        *(short8*)&As[1][r0][koA] = ra0;   // ch+1 -> buf1 (loads issued 1 iter ago)
        *(short8*)&As[1][r1][koA] = ra1;
        *(short8*)&Bs[1][r0][koA] = rb0;
        *(short8*)&Bs[1][r1][koA] = rb1;
        __syncthreads();
        // ODD chunk ch+1: compute buf1; S holds ch+2; issue R <- ch+3.
        if (ch + 3 < 16) {
            const int off = (ch + 3) * 64;
            ra0 = *(const short8*)(pA0 + off);
            ra1 = *(const short8*)(pA1 + off);
            rb0 = *(const short8*)(pB0 + off);
            rb1 = *(const short8*)(pB1 + off);
        }
        MFMA_FROM(1)
        if (ch + 2 < 16) {
            *(short8*)&As[0][r0][koA] = sa0;   // ch+2 -> buf0
            *(short8*)&As[0][r1][koA] = sa1;
            *(short8*)&Bs[0][r0][koA] = sb0;
            *(short8*)&Bs[0][r1][koA] = sb1;
            __syncthreads();
        }
    }
#undef MFMA_FROM

    // Epilogue: C/D layout col=lane&15, row=quad*4+reg -> lane's 4 regs = graph b, m=0..3
    #pragma unroll
    for (int mi = 0; mi < 2; mi++) {
        const int grow = row0 + wm * 32 + mi * 16 + quad * 4;
        const int b = grow >> 2;
        float sn0 = 0.f, sn1 = 0.f, sn2 = 0.f, sn3 = 0.f;
        #pragma unroll
        for (int ni = 0; ni < 2; ni++) {
            int gc = col0 + wn * 32 + ni * 16 + l16;
            floatx4 a = acc[mi][ni];
            if (gc < EE) {
                float bias = bA[gc];
                float l0 = a[0] + bias, l1 = a[1] + bias, l2 = a[2] + bias, l3 = a[3] + bias;
                Lbar[b * EE + gc] = 0.25f * (l0 + l1 + l2 + l3);
                sn0 += logsigm(l0); sn1 += logsigm(l1); sn2 += logsigm(l2); sn3 += logsigm(l3);
            } else if (gc < CTOT) {
                int c2 = gc - EE;
                float bias = bF[c2];
                lgF[(b * 4 + 0) * 150 + c2] = a[0] + bias;
                lgF[(b * 4 + 1) * 150 + c2] = a[1] + bias;
                lgF[(b * 4 + 2) * 150 + c2] = a[2] + bias;
                lgF[(b * 4 + 3) * 150 + c2] = a[3] + bias;
            }
        }
        #pragma unroll
        for (int msk = 1; msk < 16; msk <<= 1) {
            sn0 += __shfl_xor(sn0, msk);
            sn1 += __shfl_xor(sn1, msk);
            sn2 += __shfl_xor(sn2, msk);
            sn3 += __shfl_xor(sn3, msk);
        }
        if (l16 == 0) {
            const int o = ct * 2 + wn;
            SnegP[(b * 4 + 0) * 44 + o] = sn0;
            SnegP[(b * 4 + 1) * 44 + o] = sn1;
            SnegP[(b * 4 + 2) * 44 + o] = sn2;
            SnegP[(b * 4 + 3) * 44 + o] = sn3;
        }
    }
}

// K4: per-graph finalization. grid 256, 512 threads (8 waves).
// lane = permutation (64 lanes = 64 perms), wave = edge-stripe (8-way).
// Also reduces the 44 SnegP partials per (b,m) (no global atomics anywhere).
__global__ __launch_bounds__(512) void k4(const float* __restrict__ Fx,
                                          const float* __restrict__ coeff,
                                          const int* __restrict__ ipG,
                                          const float* __restrict__ Lbar,
                                          const float* __restrict__ SnegP,
                                          const float* __restrict__ lgF,
                                          const int* __restrict__ edgesG,
                                          const int* __restrict__ cntG,
                                          const float* __restrict__ kldG,
                                          float* __restrict__ out) {
    const int b = blockIdx.x;
    const int t = threadIdx.x;
    const int w = t >> 6, lane = t & 63;
    __shared__ int   ip[PP * 51];      // [perm][node], stride 51 (odd -> 2-way banks)
    __shared__ float LbF[NN * 51];     // full symmetric matrix
    __shared__ int   edges[256];
    __shared__ float lgfs[600];
    __shared__ float mred[4], snegR[4];
    __shared__ float psum[8][64];

    const int ne = cntG[b];
    for (int x = t; x < PP * 51; x += 512) ip[x] = ipG[x];
    for (int x = t; x < 2500; x += 512) {
        int i = x / NN, j = x - i * NN;
        if (j < i) {
            float v = Lbar[b * EE + i * (i - 1) / 2 + j];
            LbF[i * 51 + j] = v;
            LbF[j * 51 + i] = v;
        }
    }
    for (int x = t; x < 600; x += 512) lgfs[x] = lgF[b * 600 + x];
    if (t < ne) edges[t] = edgesG[b * 256 + t];
    __syncthreads();

    // perm partial sums: all 64 perms in flight per wave, edges striped by wave
    {
        const int ipB = lane * 51;
        float acc = 0.f;
        for (int x = w; x < ne; x += 8) {
            int ed = edges[x];
            int iu = ip[ipB + (ed >> 8)];
            int iv = ip[ipB + (ed & 255)];
            acc += LbF[iu * 51 + iv];
        }
        psum[w][lane] = acc;
    }

    // Fx terms + Sneg partial reduce: waves 0..3 handle sample m = w
    if (w < 4) {
        float l0 = 0.f, l1 = 0.f, l2 = -INFINITY, x0 = 0.f, x1 = 0.f, x2 = 0.f;
        bool v = lane < NN;
        if (v) {
            l0 = lgfs[w * 150 + lane * 3 + 0];
            l1 = lgfs[w * 150 + lane * 3 + 1];
            l2 = lgfs[w * 150 + lane * 3 + 2];
            x0 = Fx[b * 150 + lane * 3 + 0];
            x1 = Fx[b * 150 + lane * 3 + 1];
            x2 = Fx[b * 150 + lane * 3 + 2];
        }
        float mx = wmax64(l2);
        float es = v ? expf(l2 - mx) : 0.f;
        es = wsum64(es);
        float lse = mx + logf(es);
        float val = 0.f;
        if (v) {
            val = coeff[0] * (logsigm(l0) + x0 * l0)
                + coeff[1] * (logsigm(l1) + x1 * l1)
                + coeff[2] * (x2 * (l2 - lse));
        }
        val = wsum64(val);
        float sv = (lane < 44) ? SnegP[(b * 4 + w) * 44 + lane] : 0.f;
        sv = wsum64(sv);
        if (lane == 0) { mred[w] = val; snegR[w] = sv; }
    }
    __syncthreads();

    if (w == 0) {
        float s = psum[0][lane];
        #pragma unroll
        for (int i = 1; i < 8; i++) s += psum[i][lane];
        float dmax = wmax64(s);
        if (lane == 0) {
            float sbar = 0.25f * (snegR[0] + snegR[1] + snegR[2] + snegR[3]);
            float fxv  = 0.25f * (mred[0] + mred[1] + mred[2] + mred[3]);
            out[b] = (sbar + dmax) + fxv - kldG[b];
        }
    }
}

extern "C" void kernel_launch(void* const* d_in, const int* in_sizes, int n_in,
                              void* d_out, int out_size, void* d_ws, size_t ws_size,
                              hipStream_t stream) {
    const float* mean   = (const float*)d_in[0];
    const float* logvar = (const float*)d_in[1];
    const float* eps    = (const float*)d_in[2];
    const float* W1     = (const float*)d_in[3];
    const float* b1     = (const float*)d_in[4];
    const float* WA     = (const float*)d_in[5];
    const float* bA     = (const float*)d_in[6];
    const float* WF     = (const float*)d_in[7];
    const float* bF     = (const float*)d_in[8];
    const float* A      = (const float*)d_in[9];
    const float* Fx     = (const float*)d_in[10];
    const float* coeff  = (const float*)d_in[11];
    const int*   perms  = (const int*)d_in[12];
    float* out = (float*)d_out;

    ushort* Wt   = (ushort*)d_ws;               // 1408*1024 bf16
    ushort* hB   = Wt + NPAD * 1024;            // 1024*1024 bf16
    float*  Lbar = (float*)(hB + 1024 * 1024);  // 256*1225
    float*  SnegP = Lbar + BB * EE;             // 256*4*44 partials (written by k2)
    float*  lgF  = SnegP + 256 * 4 * 44;        // 1024*150
    int*    edgesG = (int*)(lgF + 1024 * 150);  // 256*256
    int*    cntG   = edgesG + 256 * 256;        // 256
    float*  kldG   = (float*)(cntG + 256);      // 256
    int*    ipG    = (int*)(kldG + 256);        // 64*51

    kA<<<dim3(612), dim3(256), 0, stream>>>(mean, logvar, eps, W1, b1, WA, WF, A, perms,
                                            hB, Wt, edgesG, cntG, kldG, ipG);
    k2<<<dim3(22, 16), dim3(256), 0, stream>>>(hB, Wt, bA, bF, Lbar, SnegP, lgF);
    k4<<<dim3(BB), dim3(512), 0, stream>>>(Fx, coeff, ipG, Lbar, SnegP, lgF,
                                           edgesG, cntG, kldG, out);
}

// Round 8
// 117.756 us; speedup vs baseline: 1.6019x; 1.0199x over previous
//
#include <hip/hip_runtime.h>
#include <math.h>

// Problem constants
#define MM 4
#define BB 256
#define KK 64
#define HH 1024
#define NN 50
#define EE 1225
#define PP 64
#define CTOT 1375   // E + N*3
#define NPAD 1408   // cols padded to 22*64

// History: R3 5x-launch: k2 ~ 12-13 us. R5 no-LDS k2 +16 us (uncoalesced).
// R6 revert = 123.8. R7 2-deep prefetch = 120.1 (k2 ~ 8-9 us, theory
// confirmed). R8: retile k2 64x64 -> 32x64, grid 704 = 2.75 blocks/CU so
// co-resident blocks hide each other's barrier/latency stalls (TLP fix;
// same mechanism as R1's win). LDS 27.6KB, 2-deep prefetch retained.

typedef short short8 __attribute__((ext_vector_type(8)));
typedef float floatx4 __attribute__((ext_vector_type(4)));
typedef unsigned short ushort;

__device__ __forceinline__ ushort f2bf(float f) {
    union { float f; unsigned u; } v; v.f = f;
    unsigned r = v.u + 0x7fffu + ((v.u >> 16) & 1u);
    return (ushort)(r >> 16);
}

__device__ __forceinline__ float logsigm(float l) {
    // log sigmoid(-l) = -(max(l,0) + log1p(exp(-|l|)))
    return -(fmaxf(l, 0.0f) + log1pf(expf(-fabsf(l))));
}

__device__ __forceinline__ float wsum64(float v) {
    #pragma unroll
    for (int m = 1; m < 64; m <<= 1) v += __shfl_xor(v, m);
    return v;
}
__device__ __forceinline__ float wmax64(float v) {
    #pragma unroll
    for (int m = 1; m < 64; m <<= 1) v = fmaxf(v, __shfl_xor(v, m));
    return v;
}

// kA: fused weight transpose (blocks 256..607) + per-graph work (blocks 0..255)
// + perm-inverse table build (blocks 608..611, graph-independent, feeds k4).
// NOTE (prior session): keep a plain 3-kernel chain. Cooperative grid-sync
// fusion cost +78 us; atomic producer-consumer +46 us.
__global__ __launch_bounds__(256) void kA(const float* __restrict__ mean,
                                          const float* __restrict__ logvar,
                                          const float* __restrict__ eps,
                                          const float* __restrict__ W1,
                                          const float* __restrict__ b1,
                                          const float* __restrict__ WA,
                                          const float* __restrict__ WF,
                                          const float* __restrict__ A,
                                          const int*   __restrict__ perms,
                                          ushort* __restrict__ hB,
                                          ushort* __restrict__ Wt,
                                          int*   __restrict__ edgesG,
                                          int*   __restrict__ cntG,
                                          float* __restrict__ kldG,
                                          int*   __restrict__ ipG) {
    const int t = threadIdx.x;
    __shared__ float smem[64 * 65];
    __shared__ int cnt;

    if (blockIdx.x < 256) {
        // ---- per-graph block ----
        const int b = blockIdx.x;
        float4* z4 = (float4*)smem;
        if (t == 0) cnt = 0;
        if (t < 64) {
            float mv = mean[b * 64 + t];
            float lv = logvar[b * 64 + t];
            float sd = expf(0.5f * lv);
            float4 z;
            z.x = mv + sd * eps[(0 * BB + b) * 64 + t];
            z.y = mv + sd * eps[(1 * BB + b) * 64 + t];
            z.z = mv + sd * eps[(2 * BB + b) * 64 + t];
            z.w = mv + sd * eps[(3 * BB + b) * 64 + t];
            z4[t] = z;
            // KLD (wave 0, one lane per latent dim)
            float term = 0.5f * (expf(lv) + mv * mv - 1.0f - lv);
            term = wsum64(term);
            if (t == 0) kldG[b] = term;
        }
        __syncthreads();
        const int j0 = t * 4;
        float acc[4][4] = {};   // [m][jc]
        #pragma unroll 8
        for (int k = 0; k < 64; k++) {
            float4 w = *(const float4*)&W1[k * HH + j0];
            float4 z = z4[k];
            acc[0][0] += z.x * w.x; acc[0][1] += z.x * w.y; acc[0][2] += z.x * w.z; acc[0][3] += z.x * w.w;
            acc[1][0] += z.y * w.x; acc[1][1] += z.y * w.y; acc[1][2] += z.y * w.z; acc[1][3] += z.y * w.w;
            acc[2][0] += z.z * w.x; acc[2][1] += z.z * w.y; acc[2][2] += z.z * w.z; acc[2][3] += z.z * w.w;
            acc[3][0] += z.w * w.x; acc[3][1] += z.w * w.y; acc[3][2] += z.w * w.z; acc[3][3] += z.w * w.w;
        }
        float4 bb = *(const float4*)&b1[j0];
        #pragma unroll
        for (int m = 0; m < 4; m++) {
            unsigned u0 = ((unsigned)f2bf(fmaxf(acc[m][0] + bb.x, 0.f))) |
                          ((unsigned)f2bf(fmaxf(acc[m][1] + bb.y, 0.f)) << 16);
            unsigned u1 = ((unsigned)f2bf(fmaxf(acc[m][2] + bb.z, 0.f))) |
                          ((unsigned)f2bf(fmaxf(acc[m][3] + bb.w, 0.f)) << 16);
            uint2 u; u.x = u0; u.y = u1;
            *(uint2*)&hB[(b * 4 + m) * HH + j0] = u;
        }
        // ---- edge extraction: coalesced scan of A[b], lower triangle ----
        for (int x = t; x < 2500; x += 256) {
            int i = x / NN, j = x - i * NN;
            if (j < i) {
                float a = A[b * 2500 + x];
                if (a != 0.0f) { int id = atomicAdd(&cnt, 1); edgesG[b * 256 + id] = (i << 8) | j; }
            }
        }
        __syncthreads();
        if (t == 0) cntG[b] = cnt;
    } else if (blockIdx.x < 608) {
        // ---- Wt[n][k] = transpose of [WA | WF] (bf16, zero-padded cols) ----
        const int id = blockIdx.x - 256;
        const int kt = id & 15, nt = id >> 4;
        float* T = smem;   // [64][65]
        const int k0 = kt * 64, n0 = nt * 64;
        #pragma unroll
        for (int i = 0; i < 16; i++) {
            int x = i * 256 + t;
            int kk = x >> 6, nn = x & 63;
            int gn = n0 + nn, gk = k0 + kk;
            float v = 0.f;
            if (gn < EE)        v = WA[gk * EE + gn];
            else if (gn < CTOT) v = WF[gk * 150 + (gn - EE)];
            T[kk * 65 + nn] = v;
        }
        __syncthreads();
        #pragma unroll
        for (int i = 0; i < 16; i++) {
            int x = i * 256 + t;
            int nn = x >> 6, kk = x & 63;
            Wt[(n0 + nn) * 1024 + k0 + kk] = f2bf(T[kk * 65 + nn]);
        }
    } else {
        // ---- ipG[p][node] = position of node in perm p (stride 51, b-independent) ----
        const int id = blockIdx.x - 608;   // 0..3, 16 perms each
        for (int x = id * 800 + t; x < (id + 1) * 800; x += 256) {
            int p = x / NN, i = x - p * NN;
            ipG[p * 51 + perms[x]] = i;
        }
    }
}

// K2: MFMA GEMM logits[1024][1375] = hB @ Wt^T with fused epilogue.
// R8: 32x64 tile, grid 22x32 = 704 blocks (~2.75 blocks/CU) so co-resident
// blocks hide each other's barrier/latency stalls. 4 waves (2x2): wave =
// 16 rows x 32 cols = 1x2 MFMA 16x16x32. 2-deep register prefetch (R/S sets,
// 3 short8 each). A staged by all 256 threads (1 short8), B by 2. LDS 27.6KB.
__global__ __launch_bounds__(256) void k2(const ushort* __restrict__ hB,
                                          const ushort* __restrict__ Wt,
                                          const float* __restrict__ bA,
                                          const float* __restrict__ bF,
                                          float* __restrict__ Lbar,
                                          float* __restrict__ SnegP,
                                          float* __restrict__ lgF) {
    const int ct = blockIdx.x;   // 0..21
    const int rt = blockIdx.y;   // 0..31
    const int t = threadIdx.x;
    const int w = t >> 6, lane = t & 63;
    const int wm = w >> 1, wn = w & 1;
    const int quad = lane >> 4, l16 = lane & 15;
    __shared__ short As[2][32][72];
    __shared__ short Bs[2][64][72];
    floatx4 acc[2] = {};
    const int row0 = rt * 32, col0 = ct * 64;

    const int r0 = t >> 3, koA = (t & 7) * 8;
    const ushort* pA0 = hB + (row0 + r0) * 1024 + koA;   // 32 rows x 8 loaders
    const ushort* pB0 = Wt + (col0 + r0) * 1024 + koA;
    const ushort* pB1 = pB0 + 32 * 1024;

    short8 ra0, rb0, rb1;   // set R: chunk ch+1 in flight
    short8 sa0, sb0, sb1;   // set S: chunk ch+2 in flight

#define MFMA_FROM(B) { \
        _Pragma("unroll") \
        for (int kk = 0; kk < 2; kk++) { \
            int ko = kk * 32 + quad * 8; \
            short8 a0 = *(const short8*)&As[B][wm * 16 + l16][ko]; \
            short8 b0 = *(const short8*)&Bs[B][wn * 32 + l16][ko]; \
            short8 b1 = *(const short8*)&Bs[B][wn * 32 + 16 + l16][ko]; \
            acc[0] = __builtin_amdgcn_mfma_f32_16x16x32_bf16(a0, b0, acc[0], 0, 0, 0); \
            acc[1] = __builtin_amdgcn_mfma_f32_16x16x32_bf16(a0, b1, acc[1], 0, 0, 0); \
        } }

    // Prologue: chunk 0 -> buf0; issue chunk 1 into R.
    ra0 = *(const short8*)(pA0);
    rb0 = *(const short8*)(pB0);
    rb1 = *(const short8*)(pB1);
    *(short8*)&As[0][r0][koA] = ra0;
    *(short8*)&Bs[0][r0][koA] = rb0;
    *(short8*)&Bs[0][r0 + 32][koA] = rb1;
    ra0 = *(const short8*)(pA0 + 64);
    rb0 = *(const short8*)(pB0 + 64);
    rb1 = *(const short8*)(pB1 + 64);
    __syncthreads();

    #pragma unroll
    for (int ch = 0; ch < 16; ch += 2) {
        // EVEN chunk ch: compute buf0; R holds ch+1; issue S <- ch+2.
        if (ch + 2 < 16) {
            const int off = (ch + 2) * 64;
            sa0 = *(const short8*)(pA0 + off);
            sb0 = *(const short8*)(pB0 + off);
            sb1 = *(const short8*)(pB1 + off);
        }
        MFMA_FROM(0)
        *(short8*)&As[1][r0][koA] = ra0;   // ch+1 -> buf1 (issued 1 iter ago)
        *(short8*)&Bs[1][r0][koA] = rb0;
        *(short8*)&Bs[1][r0 + 32][koA] = rb1;
        __syncthreads();
        // ODD chunk ch+1: compute buf1; S holds ch+2; issue R <- ch+3.
        if (ch + 3 < 16) {
            const int off = (ch + 3) * 64;
            ra0 = *(const short8*)(pA0 + off);
            rb0 = *(const short8*)(pB0 + off);
            rb1 = *(const short8*)(pB1 + off);
        }
        MFMA_FROM(1)
        if (ch + 2 < 16) {
            *(short8*)&As[0][r0][koA] = sa0;   // ch+2 -> buf0
            *(short8*)&Bs[0][r0][koA] = sb0;
            *(short8*)&Bs[0][r0 + 32][koA] = sb1;
            __syncthreads();
        }
    }
#undef MFMA_FROM

    // Epilogue: C/D layout col=lane&15, row=quad*4+reg -> lane's 4 regs = graph b, m=0..3
    {
        const int grow = row0 + wm * 16 + quad * 4;
        const int b = grow >> 2;
        float sn0 = 0.f, sn1 = 0.f, sn2 = 0.f, sn3 = 0.f;
        #pragma unroll
        for (int ni = 0; ni < 2; ni++) {
            int gc = col0 + wn * 32 + ni * 16 + l16;
            floatx4 a = acc[ni];
            if (gc < EE) {
                float bias = bA[gc];
                float l0 = a[0] + bias, l1 = a[1] + bias, l2 = a[2] + bias, l3 = a[3] + bias;
                Lbar[b * EE + gc] = 0.25f * (l0 + l1 + l2 + l3);
                sn0 += logsigm(l0); sn1 += logsigm(l1); sn2 += logsigm(l2); sn3 += logsigm(l3);
            } else if (gc < CTOT) {
                int c2 = gc - EE;
                float bias = bF[c2];
                lgF[(b * 4 + 0) * 150 + c2] = a[0] + bias;
                lgF[(b * 4 + 1) * 150 + c2] = a[1] + bias;
                lgF[(b * 4 + 2) * 150 + c2] = a[2] + bias;
                lgF[(b * 4 + 3) * 150 + c2] = a[3] + bias;
            }
        }
        #pragma unroll
        for (int msk = 1; msk < 16; msk <<= 1) {
            sn0 += __shfl_xor(sn0, msk);
            sn1 += __shfl_xor(sn1, msk);
            sn2 += __shfl_xor(sn2, msk);
            sn3 += __shfl_xor(sn3, msk);
        }
        if (l16 == 0) {
            const int o = ct * 2 + wn;
            SnegP[(b * 4 + 0) * 44 + o] = sn0;
            SnegP[(b * 4 + 1) * 44 + o] = sn1;
            SnegP[(b * 4 + 2) * 44 + o] = sn2;
            SnegP[(b * 4 + 3) * 44 + o] = sn3;
        }
    }
}

// K4: per-graph finalization. grid 256, 512 threads (8 waves).
// lane = permutation (64 lanes = 64 perms), wave = edge-stripe (8-way).
// Also reduces the 44 SnegP partials per (b,m) (no global atomics anywhere).
__global__ __launch_bounds__(512) void k4(const float* __restrict__ Fx,
                                          const float* __restrict__ coeff,
                                          const int* __restrict__ ipG,
                                          const float* __restrict__ Lbar,
                                          const float* __restrict__ SnegP,
                                          const float* __restrict__ lgF,
                                          const int* __restrict__ edgesG,
                                          const int* __restrict__ cntG,
                                          const float* __restrict__ kldG,
                                          float* __restrict__ out) {
    const int b = blockIdx.x;
    const int t = threadIdx.x;
    const int w = t >> 6, lane = t & 63;
    __shared__ int   ip[PP * 51];      // [perm][node], stride 51 (odd -> 2-way banks)
    __shared__ float LbF[NN * 51];     // full symmetric matrix
    __shared__ int   edges[256];
    __shared__ float lgfs[600];
    __shared__ float mred[4], snegR[4];
    __shared__ float psum[8][64];

    const int ne = cntG[b];
    for (int x = t; x < PP * 51; x += 512) ip[x] = ipG[x];
    for (int x = t; x < 2500; x += 512) {
        int i = x / NN, j = x - i * NN;
        if (j < i) {
            float v = Lbar[b * EE + i * (i - 1) / 2 + j];
            LbF[i * 51 + j] = v;
            LbF[j * 51 + i] = v;
        }
    }
    for (int x = t; x < 600; x += 512) lgfs[x] = lgF[b * 600 + x];
    if (t < ne) edges[t] = edgesG[b * 256 + t];
    __syncthreads();

    // perm partial sums: all 64 perms in flight per wave, edges striped by wave
    {
        const int ipB = lane * 51;
        float acc = 0.f;
        for (int x = w; x < ne; x += 8) {
            int ed = edges[x];
            int iu = ip[ipB + (ed >> 8)];
            int iv = ip[ipB + (ed & 255)];
            acc += LbF[iu * 51 + iv];
        }
        psum[w][lane] = acc;
    }

    // Fx terms + Sneg partial reduce: waves 0..3 handle sample m = w
    if (w < 4) {
        float l0 = 0.f, l1 = 0.f, l2 = -INFINITY, x0 = 0.f, x1 = 0.f, x2 = 0.f;
        bool v = lane < NN;
        if (v) {
            l0 = lgfs[w * 150 + lane * 3 + 0];
            l1 = lgfs[w * 150 + lane * 3 + 1];
            l2 = lgfs[w * 150 + lane * 3 + 2];
            x0 = Fx[b * 150 + lane * 3 + 0];
            x1 = Fx[b * 150 + lane * 3 + 1];
            x2 = Fx[b * 150 + lane * 3 + 2];
        }
        float mx = wmax64(l2);
        float es = v ? expf(l2 - mx) : 0.f;
        es = wsum64(es);
        float lse = mx + logf(es);
        float val = 0.f;
        if (v) {
            val = coeff[0] * (logsigm(l0) + x0 * l0)
                + coeff[1] * (logsigm(l1) + x1 * l1)
                + coeff[2] * (x2 * (l2 - lse));
        }
        val = wsum64(val);
        float sv = (lane < 44) ? SnegP[(b * 4 + w) * 44 + lane] : 0.f;
        sv = wsum64(sv);
        if (lane == 0) { mred[w] = val; snegR[w] = sv; }
    }
    __syncthreads();

    if (w == 0) {
        float s = psum[0][lane];
        #pragma unroll
        for (int i = 1; i < 8; i++) s += psum[i][lane];
        float dmax = wmax64(s);
        if (lane == 0) {
            float sbar = 0.25f * (snegR[0] + snegR[1] + snegR[2] + snegR[3]);
            float fxv  = 0.25f * (mred[0] + mred[1] + mred[2] + mred[3]);
            out[b] = (sbar + dmax) + fxv - kldG[b];
        }
    }
}

extern "C" void kernel_launch(void* const* d_in, const int* in_sizes, int n_in,
                              void* d_out, int out_size, void* d_ws, size_t ws_size,
                              hipStream_t stream) {
    const float* mean   = (const float*)d_in[0];
    const float* logvar = (const float*)d_in[1];
    const float* eps    = (const float*)d_in[2];
    const float* W1     = (const float*)d_in[3];
    const float* b1     = (const float*)d_in[4];
    const float* WA     = (const float*)d_in[5];
    const float* bA     = (const float*)d_in[6];
    const float* WF     = (const float*)d_in[7];
    const float* bF     = (const float*)d_in[8];
    const float* A      = (const float*)d_in[9];
    const float* Fx     = (const float*)d_in[10];
    const float* coeff  = (const float*)d_in[11];
    const int*   perms  = (const int*)d_in[12];
    float* out = (float*)d_out;

    ushort* Wt   = (ushort*)d_ws;               // 1408*1024 bf16
    ushort* hB   = Wt + NPAD * 1024;            // 1024*1024 bf16
    float*  Lbar = (float*)(hB + 1024 * 1024);  // 256*1225
    float*  SnegP = Lbar + BB * EE;             // 256*4*44 partials (written by k2)
    float*  lgF  = SnegP + 256 * 4 * 44;        // 1024*150
    int*    edgesG = (int*)(lgF + 1024 * 150);  // 256*256
    int*    cntG   = edgesG + 256 * 256;        // 256
    float*  kldG   = (float*)(cntG + 256);      // 256
    int*    ipG    = (int*)(kldG + 256);        // 64*51

    kA<<<dim3(612), dim3(256), 0, stream>>>(mean, logvar, eps, W1, b1, WA, WF, A, perms,
                                            hB, Wt, edgesG, cntG, kldG, ipG);
    k2<<<dim3(22, 32), dim3(256), 0, stream>>>(hB, Wt, bA, bF, Lbar, SnegP, lgF);
    k4<<<dim3(BB), dim3(512), 0, stream>>>(Fx, coeff, ipG, Lbar, SnegP, lgF,
                                           edgesG, cntG, kldG, out);
}

// Round 9
// 114.453 us; speedup vs baseline: 1.6481x; 1.0289x over previous
//
#include <hip/hip_runtime.h>
#include <math.h>

// Problem constants
#define MM 4
#define BB 256
#define KK 64
#define HH 1024
#define NN 50
#define EE 1225
#define PP 64
#define CTOT 1375   // E + N*3
#define NPAD 1408   // cols padded to 22*64

// History: R3 5x-launch: k2 ~12-13 us. R5 no-LDS k2 +16 (uncoalesced). R6
// revert = 123.8. R7 2-deep prefetch = 120.1. R8 32x64/704-block retile =
// 117.8 (3 confirmed predictions: these kernels are latency-exposed; overlap
// capacity pays). R9: same mechanism on k4 — 512->1024 threads (2->4
// waves/SIMD) for the dependent LDS gather chains in the perm loop.

typedef short short8 __attribute__((ext_vector_type(8)));
typedef float floatx4 __attribute__((ext_vector_type(4)));
typedef unsigned short ushort;

__device__ __forceinline__ ushort f2bf(float f) {
    union { float f; unsigned u; } v; v.f = f;
    unsigned r = v.u + 0x7fffu + ((v.u >> 16) & 1u);
    return (ushort)(r >> 16);
}

__device__ __forceinline__ float logsigm(float l) {
    // log sigmoid(-l) = -(max(l,0) + log1p(exp(-|l|)))
    return -(fmaxf(l, 0.0f) + log1pf(expf(-fabsf(l))));
}

__device__ __forceinline__ float wsum64(float v) {
    #pragma unroll
    for (int m = 1; m < 64; m <<= 1) v += __shfl_xor(v, m);
    return v;
}
__device__ __forceinline__ float wmax64(float v) {
    #pragma unroll
    for (int m = 1; m < 64; m <<= 1) v = fmaxf(v, __shfl_xor(v, m));
    return v;
}

// kA: fused weight transpose (blocks 256..607) + per-graph work (blocks 0..255)
// + perm-inverse table build (blocks 608..611, graph-independent, feeds k4).
// NOTE (prior session): keep a plain 3-kernel chain. Cooperative grid-sync
// fusion cost +78 us; atomic producer-consumer +46 us.
__global__ __launch_bounds__(256) void kA(const float* __restrict__ mean,
                                          const float* __restrict__ logvar,
                                          const float* __restrict__ eps,
                                          const float* __restrict__ W1,
                                          const float* __restrict__ b1,
                                          const float* __restrict__ WA,
                                          const float* __restrict__ WF,
                                          const float* __restrict__ A,
                                          const int*   __restrict__ perms,
                                          ushort* __restrict__ hB,
                                          ushort* __restrict__ Wt,
                                          int*   __restrict__ edgesG,
                                          int*   __restrict__ cntG,
                                          float* __restrict__ kldG,
                                          int*   __restrict__ ipG) {
    const int t = threadIdx.x;
    __shared__ float smem[64 * 65];
    __shared__ int cnt;

    if (blockIdx.x < 256) {
        // ---- per-graph block ----
        const int b = blockIdx.x;
        float4* z4 = (float4*)smem;
        if (t == 0) cnt = 0;
        if (t < 64) {
            float mv = mean[b * 64 + t];
            float lv = logvar[b * 64 + t];
            float sd = expf(0.5f * lv);
            float4 z;
            z.x = mv + sd * eps[(0 * BB + b) * 64 + t];
            z.y = mv + sd * eps[(1 * BB + b) * 64 + t];
            z.z = mv + sd * eps[(2 * BB + b) * 64 + t];
            z.w = mv + sd * eps[(3 * BB + b) * 64 + t];
            z4[t] = z;
            // KLD (wave 0, one lane per latent dim)
            float term = 0.5f * (expf(lv) + mv * mv - 1.0f - lv);
            term = wsum64(term);
            if (t == 0) kldG[b] = term;
        }
        __syncthreads();
        const int j0 = t * 4;
        float acc[4][4] = {};   // [m][jc]
        #pragma unroll 8
        for (int k = 0; k < 64; k++) {
            float4 w = *(const float4*)&W1[k * HH + j0];
            float4 z = z4[k];
            acc[0][0] += z.x * w.x; acc[0][1] += z.x * w.y; acc[0][2] += z.x * w.z; acc[0][3] += z.x * w.w;
            acc[1][0] += z.y * w.x; acc[1][1] += z.y * w.y; acc[1][2] += z.y * w.z; acc[1][3] += z.y * w.w;
            acc[2][0] += z.z * w.x; acc[2][1] += z.z * w.y; acc[2][2] += z.z * w.z; acc[2][3] += z.z * w.w;
            acc[3][0] += z.w * w.x; acc[3][1] += z.w * w.y; acc[3][2] += z.w * w.z; acc[3][3] += z.w * w.w;
        }
        float4 bb = *(const float4*)&b1[j0];
        #pragma unroll
        for (int m = 0; m < 4; m++) {
            unsigned u0 = ((unsigned)f2bf(fmaxf(acc[m][0] + bb.x, 0.f))) |
                          ((unsigned)f2bf(fmaxf(acc[m][1] + bb.y, 0.f)) << 16);
            unsigned u1 = ((unsigned)f2bf(fmaxf(acc[m][2] + bb.z, 0.f))) |
                          ((unsigned)f2bf(fmaxf(acc[m][3] + bb.w, 0.f)) << 16);
            uint2 u; u.x = u0; u.y = u1;
            *(uint2*)&hB[(b * 4 + m) * HH + j0] = u;
        }
        // ---- edge extraction: coalesced scan of A[b], lower triangle ----
        for (int x = t; x < 2500; x += 256) {
            int i = x / NN, j = x - i * NN;
            if (j < i) {
                float a = A[b * 2500 + x];
                if (a != 0.0f) { int id = atomicAdd(&cnt, 1); edgesG[b * 256 + id] = (i << 8) | j; }
            }
        }
        __syncthreads();
        if (t == 0) cntG[b] = cnt;
    } else if (blockIdx.x < 608) {
        // ---- Wt[n][k] = transpose of [WA | WF] (bf16, zero-padded cols) ----
        const int id = blockIdx.x - 256;
        const int kt = id & 15, nt = id >> 4;
        float* T = smem;   // [64][65]
        const int k0 = kt * 64, n0 = nt * 64;
        #pragma unroll
        for (int i = 0; i < 16; i++) {
            int x = i * 256 + t;
            int kk = x >> 6, nn = x & 63;
            int gn = n0 + nn, gk = k0 + kk;
            float v = 0.f;
            if (gn < EE)        v = WA[gk * EE + gn];
            else if (gn < CTOT) v = WF[gk * 150 + (gn - EE)];
            T[kk * 65 + nn] = v;
        }
        __syncthreads();
        #pragma unroll
        for (int i = 0; i < 16; i++) {
            int x = i * 256 + t;
            int nn = x >> 6, kk = x & 63;
            Wt[(n0 + nn) * 1024 + k0 + kk] = f2bf(T[kk * 65 + nn]);
        }
    } else {
        // ---- ipG[p][node] = position of node in perm p (stride 51, b-independent) ----
        const int id = blockIdx.x - 608;   // 0..3, 16 perms each
        for (int x = id * 800 + t; x < (id + 1) * 800; x += 256) {
            int p = x / NN, i = x - p * NN;
            ipG[p * 51 + perms[x]] = i;
        }
    }
}

// K2: MFMA GEMM logits[1024][1375] = hB @ Wt^T with fused epilogue.
// R8 structure (kept): 32x64 tile, grid 22x32 = 704 blocks (~2.75 blocks/CU),
// 4 waves (2x2), 2-deep register prefetch (R/S sets). LDS 27.6KB.
__global__ __launch_bounds__(256) void k2(const ushort* __restrict__ hB,
                                          const ushort* __restrict__ Wt,
                                          const float* __restrict__ bA,
                                          const float* __restrict__ bF,
                                          float* __restrict__ Lbar,
                                          float* __restrict__ SnegP,
                                          float* __restrict__ lgF) {
    const int ct = blockIdx.x;   // 0..21
    const int rt = blockIdx.y;   // 0..31
    const int t = threadIdx.x;
    const int w = t >> 6, lane = t & 63;
    const int wm = w >> 1, wn = w & 1;
    const int quad = lane >> 4, l16 = lane & 15;
    __shared__ short As[2][32][72];
    __shared__ short Bs[2][64][72];
    floatx4 acc[2] = {};
    const int row0 = rt * 32, col0 = ct * 64;

    const int r0 = t >> 3, koA = (t & 7) * 8;
    const ushort* pA0 = hB + (row0 + r0) * 1024 + koA;   // 32 rows x 8 loaders
    const ushort* pB0 = Wt + (col0 + r0) * 1024 + koA;
    const ushort* pB1 = pB0 + 32 * 1024;

    short8 ra0, rb0, rb1;   // set R: chunk ch+1 in flight
    short8 sa0, sb0, sb1;   // set S: chunk ch+2 in flight

#define MFMA_FROM(B) { \
        _Pragma("unroll") \
        for (int kk = 0; kk < 2; kk++) { \
            int ko = kk * 32 + quad * 8; \
            short8 a0 = *(const short8*)&As[B][wm * 16 + l16][ko]; \
            short8 b0 = *(const short8*)&Bs[B][wn * 32 + l16][ko]; \
            short8 b1 = *(const short8*)&Bs[B][wn * 32 + 16 + l16][ko]; \
            acc[0] = __builtin_amdgcn_mfma_f32_16x16x32_bf16(a0, b0, acc[0], 0, 0, 0); \
            acc[1] = __builtin_amdgcn_mfma_f32_16x16x32_bf16(a0, b1, acc[1], 0, 0, 0); \
        } }

    // Prologue: chunk 0 -> buf0; issue chunk 1 into R.
    ra0 = *(const short8*)(pA0);
    rb0 = *(const short8*)(pB0);
    rb1 = *(const short8*)(pB1);
    *(short8*)&As[0][r0][koA] = ra0;
    *(short8*)&Bs[0][r0][koA] = rb0;
    *(short8*)&Bs[0][r0 + 32][koA] = rb1;
    ra0 = *(const short8*)(pA0 + 64);
    rb0 = *(const short8*)(pB0 + 64);
    rb1 = *(const short8*)(pB1 + 64);
    __syncthreads();

    #pragma unroll
    for (int ch = 0; ch < 16; ch += 2) {
        // EVEN chunk ch: compute buf0; R holds ch+1; issue S <- ch+2.
        if (ch + 2 < 16) {
            const int off = (ch + 2) * 64;
            sa0 = *(const short8*)(pA0 + off);
            sb0 = *(const short8*)(pB0 + off);
            sb1 = *(const short8*)(pB1 + off);
        }
        MFMA_FROM(0)
        *(short8*)&As[1][r0][koA] = ra0;   // ch+1 -> buf1 (issued 1 iter ago)
        *(short8*)&Bs[1][r0][koA] = rb0;
        *(short8*)&Bs[1][r0 + 32][koA] = rb1;
        __syncthreads();
        // ODD chunk ch+1: compute buf1; S holds ch+2; issue R <- ch+3.
        if (ch + 3 < 16) {
            const int off = (ch + 3) * 64;
            ra0 = *(const short8*)(pA0 + off);
            rb0 = *(const short8*)(pB0 + off);
            rb1 = *(const short8*)(pB1 + off);
        }
        MFMA_FROM(1)
        if (ch + 2 < 16) {
            *(short8*)&As[0][r0][koA] = sa0;   // ch+2 -> buf0
            *(short8*)&Bs[0][r0][koA] = sb0;
            *(short8*)&Bs[0][r0 + 32][koA] = sb1;
            __syncthreads();
        }
    }
#undef MFMA_FROM

    // Epilogue: C/D layout col=lane&15, row=quad*4+reg -> lane's 4 regs = graph b, m=0..3
    {
        const int grow = row0 + wm * 16 + quad * 4;
        const int b = grow >> 2;
        float sn0 = 0.f, sn1 = 0.f, sn2 = 0.f, sn3 = 0.f;
        #pragma unroll
        for (int ni = 0; ni < 2; ni++) {
            int gc = col0 + wn * 32 + ni * 16 + l16;
            floatx4 a = acc[ni];
            if (gc < EE) {
                float bias = bA[gc];
                float l0 = a[0] + bias, l1 = a[1] + bias, l2 = a[2] + bias, l3 = a[3] + bias;
                Lbar[b * EE + gc] = 0.25f * (l0 + l1 + l2 + l3);
                sn0 += logsigm(l0); sn1 += logsigm(l1); sn2 += logsigm(l2); sn3 += logsigm(l3);
            } else if (gc < CTOT) {
                int c2 = gc - EE;
                float bias = bF[c2];
                lgF[(b * 4 + 0) * 150 + c2] = a[0] + bias;
                lgF[(b * 4 + 1) * 150 + c2] = a[1] + bias;
                lgF[(b * 4 + 2) * 150 + c2] = a[2] + bias;
                lgF[(b * 4 + 3) * 150 + c2] = a[3] + bias;
            }
        }
        #pragma unroll
        for (int msk = 1; msk < 16; msk <<= 1) {
            sn0 += __shfl_xor(sn0, msk);
            sn1 += __shfl_xor(sn1, msk);
            sn2 += __shfl_xor(sn2, msk);
            sn3 += __shfl_xor(sn3, msk);
        }
        if (l16 == 0) {
            const int o = ct * 2 + wn;
            SnegP[(b * 4 + 0) * 44 + o] = sn0;
            SnegP[(b * 4 + 1) * 44 + o] = sn1;
            SnegP[(b * 4 + 2) * 44 + o] = sn2;
            SnegP[(b * 4 + 3) * 44 + o] = sn3;
        }
    }
}

// K4: per-graph finalization. grid 256.
// R9: 1024 threads (16 waves = 4 waves/SIMD, was 2). The perm loop is a
// 2-deep dependent LDS gather chain; doubling wave count doubles both the
// edge-stripe parallelism (12 iters/wave vs 23) and the TLP available to
// hide the chain latency. Same mechanism as R7/R8's confirmed wins.
__global__ __launch_bounds__(1024) void k4(const float* __restrict__ Fx,
                                           const float* __restrict__ coeff,
                                           const int* __restrict__ ipG,
                                           const float* __restrict__ Lbar,
                                           const float* __restrict__ SnegP,
                                           const float* __restrict__ lgF,
                                           const int* __restrict__ edgesG,
                                           const int* __restrict__ cntG,
                                           const float* __restrict__ kldG,
                                           float* __restrict__ out) {
    const int b = blockIdx.x;
    const int t = threadIdx.x;
    const int w = t >> 6, lane = t & 63;
    __shared__ int   ip[PP * 51];      // [perm][node], stride 51 (odd -> 2-way banks)
    __shared__ float LbF[NN * 51];     // full symmetric matrix
    __shared__ int   edges[256];
    __shared__ float lgfs[600];
    __shared__ float mred[4], snegR[4];
    __shared__ float psum[16][64];

    const int ne = cntG[b];
    for (int x = t; x < PP * 51; x += 1024) ip[x] = ipG[x];
    for (int x = t; x < 2500; x += 1024) {
        int i = x / NN, j = x - i * NN;
        if (j < i) {
            float v = Lbar[b * EE + i * (i - 1) / 2 + j];
            LbF[i * 51 + j] = v;
            LbF[j * 51 + i] = v;
        }
    }
    if (t < 600) lgfs[t] = lgF[b * 600 + t];
    if (t < ne) edges[t] = edgesG[b * 256 + t];
    __syncthreads();

    // perm partial sums: all 64 perms in flight per wave, edges striped by wave
    {
        const int ipB = lane * 51;
        float acc = 0.f;
        for (int x = w; x < ne; x += 16) {
            int ed = edges[x];
            int iu = ip[ipB + (ed >> 8)];
            int iv = ip[ipB + (ed & 255)];
            acc += LbF[iu * 51 + iv];
        }
        psum[w][lane] = acc;
    }

    // Fx terms + Sneg partial reduce: waves 0..3 handle sample m = w
    if (w < 4) {
        float l0 = 0.f, l1 = 0.f, l2 = -INFINITY, x0 = 0.f, x1 = 0.f, x2 = 0.f;
        bool v = lane < NN;
        if (v) {
            l0 = lgfs[w * 150 + lane * 3 + 0];
            l1 = lgfs[w * 150 + lane * 3 + 1];
            l2 = lgfs[w * 150 + lane * 3 + 2];
            x0 = Fx[b * 150 + lane * 3 + 0];
            x1 = Fx[b * 150 + lane * 3 + 1];
            x2 = Fx[b * 150 + lane * 3 + 2];
        }
        float mx = wmax64(l2);
        float es = v ? expf(l2 - mx) : 0.f;
        es = wsum64(es);
        float lse = mx + logf(es);
        float val = 0.f;
        if (v) {
            val = coeff[0] * (logsigm(l0) + x0 * l0)
                + coeff[1] * (logsigm(l1) + x1 * l1)
                + coeff[2] * (x2 * (l2 - lse));
        }
        val = wsum64(val);
        float sv = (lane < 44) ? SnegP[(b * 4 + w) * 44 + lane] : 0.f;
        sv = wsum64(sv);
        if (lane == 0) { mred[w] = val; snegR[w] = sv; }
    }
    __syncthreads();

    if (w == 0) {
        float s = psum[0][lane];
        #pragma unroll
        for (int i = 1; i < 16; i++) s += psum[i][lane];
        float dmax = wmax64(s);
        if (lane == 0) {
            float sbar = 0.25f * (snegR[0] + snegR[1] + snegR[2] + snegR[3]);
            float fxv  = 0.25f * (mred[0] + mred[1] + mred[2] + mred[3]);
            out[b] = (sbar + dmax) + fxv - kldG[b];
        }
    }
}

extern "C" void kernel_launch(void* const* d_in, const int* in_sizes, int n_in,
                              void* d_out, int out_size, void* d_ws, size_t ws_size,
                              hipStream_t stream) {
    const float* mean   = (const float*)d_in[0];
    const float* logvar = (const float*)d_in[1];
    const float* eps    = (const float*)d_in[2];
    const float* W1     = (const float*)d_in[3];
    const float* b1     = (const float*)d_in[4];
    const float* WA     = (const float*)d_in[5];
    const float* bA     = (const float*)d_in[6];
    const float* WF     = (const float*)d_in[7];
    const float* bF     = (const float*)d_in[8];
    const float* A      = (const float*)d_in[9];
    const float* Fx     = (const float*)d_in[10];
    const float* coeff  = (const float*)d_in[11];
    const int*   perms  = (const int*)d_in[12];
    float* out = (float*)d_out;

    ushort* Wt   = (ushort*)d_ws;               // 1408*1024 bf16
    ushort* hB   = Wt + NPAD * 1024;            // 1024*1024 bf16
    float*  Lbar = (float*)(hB + 1024 * 1024);  // 256*1225
    float*  SnegP = Lbar + BB * EE;             // 256*4*44 partials (written by k2)
    float*  lgF  = SnegP + 256 * 4 * 44;        // 1024*150
    int*    edgesG = (int*)(lgF + 1024 * 150);  // 256*256
    int*    cntG   = edgesG + 256 * 256;        // 256
    float*  kldG   = (float*)(cntG + 256);      // 256
    int*    ipG    = (int*)(kldG + 256);        // 64*51

    kA<<<dim3(612), dim3(256), 0, stream>>>(mean, logvar, eps, W1, b1, WA, WF, A, perms,
                                            hB, Wt, edgesG, cntG, kldG, ipG);
    k2<<<dim3(22, 32), dim3(256), 0, stream>>>(hB, Wt, bA, bF, Lbar, SnegP, lgF);
    k4<<<dim3(BB), dim3(1024), 0, stream>>>(Fx, coeff, ipG, Lbar, SnegP, lgF,
                                            edgesG, cntG, kldG, out);
}